// Round 6
// baseline (446.865 us; speedup 1.0000x reference)
//
#include <hip/hip_runtime.h>
#include <cstdint>
#include <cstddef>

typedef unsigned short u16;
typedef __attribute__((ext_vector_type(8))) short bf16x8;
typedef __attribute__((ext_vector_type(4))) float f32x4;
typedef __attribute__((ext_vector_type(4))) u16 u16x4;
typedef __attribute__((address_space(1))) const unsigned int gu32;
typedef __attribute__((address_space(3))) unsigned int lu32;

#define QSCALE 0.1803368801111204f  // 0.125 * log2(e): softmax done in exp2 domain

__device__ __forceinline__ u16 f2bf(float f) {
  uint32_t u = __float_as_uint(f);
  u += 0x7fffu + ((u >> 16) & 1u);
  return (u16)(u >> 16);
}

// ---------------- transpose fp32 (K,N) -> bf16 (N,K) ----------------
__global__ __launch_bounds__(256) void transpose_w(const float* __restrict__ W,
                                                   u16* __restrict__ WT,
                                                   int K, int N) {
  __shared__ float t[32][33];
  int n0 = blockIdx.x * 32, k0 = blockIdx.y * 32;
  for (int i = threadIdx.y; i < 32; i += 8)
    t[i][threadIdx.x] = W[(size_t)(k0 + i) * N + n0 + threadIdx.x];
  __syncthreads();
  for (int i = threadIdx.y; i < 32; i += 8)
    WT[(size_t)(n0 + i) * K + k0 + threadIdx.x] = f2bf(t[threadIdx.x][i]);
}

// ---------------- layernorm fp32 row(1024) -> bf16 ----------------
__global__ __launch_bounds__(256) void ln_kernel(const float* __restrict__ x,
                                                 const float* __restrict__ g,
                                                 const float* __restrict__ b,
                                                 u16* __restrict__ out) {
  int row = blockIdx.x;
  const float4 v = *(const float4*)(x + (size_t)row * 1024 + threadIdx.x * 4);
  float s = v.x + v.y + v.z + v.w;
  float ss = v.x * v.x + v.y * v.y + v.z * v.z + v.w * v.w;
#pragma unroll
  for (int d = 1; d < 64; d <<= 1) { s += __shfl_xor(s, d); ss += __shfl_xor(ss, d); }
  __shared__ float rs_[4], rss_[4];
  int wv = threadIdx.x >> 6;
  if ((threadIdx.x & 63) == 0) { rs_[wv] = s; rss_[wv] = ss; }
  __syncthreads();
  s = rs_[0] + rs_[1] + rs_[2] + rs_[3];
  ss = rss_[0] + rss_[1] + rss_[2] + rss_[3];
  float mu = s * (1.f / 1024.f);
  float var = ss * (1.f / 1024.f) - mu * mu;
  float rstd = rsqrtf(var + 1e-5f);
  float4 gv = *(const float4*)(g + threadIdx.x * 4);
  float4 bv = *(const float4*)(b + threadIdx.x * 4);
  uint32_t lo = (uint32_t)f2bf((v.x - mu) * rstd * gv.x + bv.x) |
                ((uint32_t)f2bf((v.y - mu) * rstd * gv.y + bv.y) << 16);
  uint32_t hi = (uint32_t)f2bf((v.z - mu) * rstd * gv.z + bv.z) |
                ((uint32_t)f2bf((v.w - mu) * rstd * gv.w + bv.w) << 16);
  uint2 o; o.x = lo; o.y = hi;
  *(uint2*)(out + (size_t)row * 1024 + threadIdx.x * 4) = o;
}

// ---------------- deep-pipelined GEMM: C = A(bf16 MxK) * BT(bf16 NxK) ----------------
// BM=256 BN=128 BK=64, 8 waves (4Mx2N), ring-3 LDS (144KB), prefetch 2 K-tiles ahead,
// counted vmcnt (6 steady), 2 phases/K-tile of 16 MFMA, T2 row-XOR swizzle, T5 setprio.
#define STAGEA(slot, tnext, is)                                               \
  __builtin_amdgcn_global_load_lds(                                           \
      (gu32*)((const char*)(A + (size_t)(bm * 256 + (is) * 64 + srow) * K +   \
                            (size_t)(tnext) * 64) + ssw),                     \
      (lu32*)&lds[(slot) * 24576 + (is) * 4096 + wid * 512], 16, 0, 0)
#define STAGEB(slot, tnext, is)                                               \
  __builtin_amdgcn_global_load_lds(                                           \
      (gu32*)((const char*)(BT + (size_t)(bn * 128 + (is) * 64 + srow) * K +  \
                            (size_t)(tnext) * 64) + ssw),                     \
      (lu32*)&lds[(slot) * 24576 + 16384 + (is) * 4096 + wid * 512], 16, 0, 0)

template <int MODE>
__global__ __launch_bounds__(512, 2) void gemm8p(
    const u16* __restrict__ A, const u16* __restrict__ BT,
    int M, int N, int K,
    const float* __restrict__ bias, const float* __restrict__ resid,
    float* __restrict__ outf,
    u16* __restrict__ ob0, u16* __restrict__ ob1, u16* __restrict__ ob2) {
  __shared__ __align__(16) u16 lds[73728];  // 3 x (A 256x64 + B 128x64) = 144 KB
  const int tid = threadIdx.x, lane = tid & 63, wid = tid >> 6;
  const int wr = wid >> 1, wc = wid & 1;
  const int bm = blockIdx.y, bn = blockIdx.x;
  const int l15 = lane & 15, lhi = lane >> 4;
  const int srow = tid >> 3;
  const int ssw = ((tid & 7) * 16) ^ ((srow & 7) << 4);
  const int cs0 = (lhi * 8) ^ ((l15 & 7) << 3);
  const int cs1 = (32 + lhi * 8) ^ ((l15 & 7) << 3);
  const int arow = (wr * 64 + l15) * 64;
  const int brow = (wc * 64 + l15) * 64;

  f32x4 acc[4][4];
#pragma unroll
  for (int i = 0; i < 4; ++i)
#pragma unroll
    for (int j = 0; j < 4; ++j) acc[i][j] = (f32x4){0.f, 0.f, 0.f, 0.f};

  const int NT = K >> 6;

  // prologue: stage tiles 0,1 into slots 0,1 (loop stages tile 2 at t=0)
#pragma unroll
  for (int t0 = 0; t0 < 2; ++t0) {
    STAGEA(t0, t0, 0); STAGEA(t0, t0, 1); STAGEA(t0, t0, 2); STAGEA(t0, t0, 3);
    STAGEB(t0, t0, 0); STAGEB(t0, t0, 1);
  }
  asm volatile("s_waitcnt vmcnt(6)" ::: "memory");  // tile 0 landed
  __builtin_amdgcn_s_barrier();

  int s = 0, sn = 2;
  for (int t = 0; t < NT; ++t) {
    const bool hasPre = (t + 2) < NT;
    const int aoff = s * 24576, boff = s * 24576 + 16384;

    bf16x8 bfr[4][2], afr[2][2];
#pragma unroll
    for (int ni = 0; ni < 4; ++ni) {
      bfr[ni][0] = *(const bf16x8*)&lds[boff + brow + ni * 1024 + cs0];
      bfr[ni][1] = *(const bf16x8*)&lds[boff + brow + ni * 1024 + cs1];
    }
    afr[0][0] = *(const bf16x8*)&lds[aoff + arow + cs0];
    afr[0][1] = *(const bf16x8*)&lds[aoff + arow + cs1];
    afr[1][0] = *(const bf16x8*)&lds[aoff + arow + 1024 + cs0];
    afr[1][1] = *(const bf16x8*)&lds[aoff + arow + 1024 + cs1];
    if (hasPre) { STAGEA(sn, t + 2, 0); STAGEA(sn, t + 2, 1); STAGEB(sn, t + 2, 0); }
    __builtin_amdgcn_s_barrier();
    __builtin_amdgcn_s_setprio(1);
#pragma unroll
    for (int ml = 0; ml < 2; ++ml)
#pragma unroll
      for (int ni = 0; ni < 4; ++ni) {
        acc[ml][ni] = __builtin_amdgcn_mfma_f32_16x16x32_bf16(afr[ml][0], bfr[ni][0], acc[ml][ni], 0, 0, 0);
        acc[ml][ni] = __builtin_amdgcn_mfma_f32_16x16x32_bf16(afr[ml][1], bfr[ni][1], acc[ml][ni], 0, 0, 0);
      }
    __builtin_amdgcn_s_setprio(0);
    __builtin_amdgcn_s_barrier();

    afr[0][0] = *(const bf16x8*)&lds[aoff + arow + 2048 + cs0];
    afr[0][1] = *(const bf16x8*)&lds[aoff + arow + 2048 + cs1];
    afr[1][0] = *(const bf16x8*)&lds[aoff + arow + 3072 + cs0];
    afr[1][1] = *(const bf16x8*)&lds[aoff + arow + 3072 + cs1];
    if (hasPre) { STAGEA(sn, t + 2, 2); STAGEA(sn, t + 2, 3); STAGEB(sn, t + 2, 1); }
    __builtin_amdgcn_s_barrier();
    __builtin_amdgcn_s_setprio(1);
#pragma unroll
    for (int ml = 0; ml < 2; ++ml)
#pragma unroll
      for (int ni = 0; ni < 4; ++ni) {
        acc[2 + ml][ni] = __builtin_amdgcn_mfma_f32_16x16x32_bf16(afr[ml][0], bfr[ni][0], acc[2 + ml][ni], 0, 0, 0);
        acc[2 + ml][ni] = __builtin_amdgcn_mfma_f32_16x16x32_bf16(afr[ml][1], bfr[ni][1], acc[2 + ml][ni], 0, 0, 0);
      }
    __builtin_amdgcn_s_setprio(0);
    if (hasPre) {
      asm volatile("s_waitcnt vmcnt(6)" ::: "memory");
    } else if (t + 1 < NT) {
      asm volatile("s_waitcnt vmcnt(0)" ::: "memory");
    }
    __builtin_amdgcn_s_barrier();

    s = (s == 2) ? 0 : s + 1;
    sn = (sn == 2) ? 0 : sn + 1;
  }

#pragma unroll
  for (int mi = 0; mi < 4; ++mi) {
#pragma unroll
    for (int ni = 0; ni < 4; ++ni) {
      int col = bn * 128 + wc * 64 + ni * 16 + l15;
      int rbase = bm * 256 + wr * 64 + mi * 16 + lhi * 4;
#pragma unroll
      for (int r = 0; r < 4; ++r) {
        float v = acc[mi][ni][r];
        int rg = rbase + r;
        if (MODE == 0) {
          int b = rg >> 11, tt = rg & 2047;
          int cm = col & 1023, h = cm >> 6, d = cm & 63;
          size_t bh = (size_t)(b * 16 + h);
          if (col < 1024)
            ob0[(bh * 2048 + tt) * 64 + d] = f2bf(v * QSCALE);
          else if (col < 2048)
            ob1[(bh * 2048 + tt) * 64 + d] = f2bf(v);
          else
            ob2[(bh * 64 + d) * 2048 + tt] = f2bf(v);
        } else if (MODE == 1) {
          outf[(size_t)rg * N + col] = v + bias[col] + resid[(size_t)rg * N + col];
        } else if (MODE == 2) {
          ob0[(size_t)rg * N + col] = f2bf(fmaxf(v + bias[col], 0.f));
        } else {
          outf[(size_t)rg * N + col] = fmaxf(v + bias[col], 0.f) + resid[(size_t)rg * N + col];
        }
      }
    }
  }
}

// ---------------- causal flash attention ----------------
// 4 waves x 32 q-rows = 128-row chunk per block; chunk pairing (15-p, p) over 16
// chunks -> 512 blocks (2/CU). Swapped QK^T in exp2 domain, global_load_lds K/V
// staging (XOR swizzle, dbuf, stage-after-barrier), defer-max, cvt_pk P-pack.
__global__ __launch_bounds__(256) void attn_kernel(
    const u16* __restrict__ Qb, const u16* __restrict__ Kb,
    const u16* __restrict__ VTb, u16* __restrict__ O) {
  const int p = blockIdx.x;  // 0..7
  const int bh = blockIdx.y;
  const u16* Q = Qb + (size_t)bh * 2048 * 64;
  const u16* Kp = Kb + (size_t)bh * 2048 * 64;
  const u16* VT = VTb + (size_t)bh * 64 * 2048;
  const int tid = threadIdx.x, lane = tid & 63, wv = tid >> 6;
  const int l15 = lane & 15, lhi = lane >> 4;
  const int srow8 = tid >> 3;            // 0..31
  const int scol16 = (tid & 7) * 16;     // byte within 128B row
  const int rswz = (l15 & 7) << 4;
  const int cb0 = (lhi * 16) ^ rswz;     // swizzled byte col, ks=0
  const int cb1 = (64 + lhi * 16) ^ rswz;
  const int b = bh >> 4, h = bh & 15;

  __shared__ __align__(16) u16 KV[2][2][4096];  // [slot][K,V][64x64] = 32 KB
  __shared__ u16 Ps[4][32 * 72];                // 18 KB

#define STAGEKV(slot, kt)                                                     \
  do {                                                                        \
    const int r0 = srow8, r1 = 32 + srow8;                                    \
    const int sw = scol16 ^ ((srow8 & 7) << 4);                               \
    __builtin_amdgcn_global_load_lds(                                         \
        (gu32*)((const char*)(Kp + (size_t)((kt)*64 + r0) * 64) + sw),        \
        (lu32*)&KV[slot][0][wv * 512], 16, 0, 0);                             \
    __builtin_amdgcn_global_load_lds(                                         \
        (gu32*)((const char*)(VT + (size_t)r0 * 2048 + (kt)*64) + sw),        \
        (lu32*)&KV[slot][1][wv * 512], 16, 0, 0);                             \
    __builtin_amdgcn_global_load_lds(                                         \
        (gu32*)((const char*)(Kp + (size_t)((kt)*64 + r1) * 64) + sw),        \
        (lu32*)&KV[slot][0][2048 + wv * 512], 16, 0, 0);                      \
    __builtin_amdgcn_global_load_lds(                                         \
        (gu32*)((const char*)(VT + (size_t)r1 * 2048 + (kt)*64) + sw),        \
        (lu32*)&KV[slot][1][2048 + wv * 512], 16, 0, 0);                      \
  } while (0)

#pragma unroll
  for (int pass = 0; pass < 2; ++pass) {
    const int chunk = pass ? p : (15 - p);
    const int qbase = chunk * 128 + wv * 32;
    const int nkt = 2 * chunk + 2;

    bf16x8 qf[2][2];
#pragma unroll
    for (int rf = 0; rf < 2; ++rf)
#pragma unroll
      for (int ks = 0; ks < 2; ++ks)
        qf[rf][ks] = *(const bf16x8*)&Q[(size_t)(qbase + rf * 16 + l15) * 64 + ks * 32 + lhi * 8];

    f32x4 o[2][4];
#pragma unroll
    for (int rf = 0; rf < 2; ++rf)
#pragma unroll
      for (int f = 0; f < 4; ++f) o[rf][f] = (f32x4){0.f, 0.f, 0.f, 0.f};
    float m[2] = {-1e30f, -1e30f};
    float l[2] = {0.f, 0.f};

    __syncthreads();  // prior pass's LDS reads complete across all waves
    STAGEKV(0, 0);

    for (int kt = 0; kt < nkt; ++kt) {
      const int cs = kt & 1;
      asm volatile("s_waitcnt vmcnt(0)" ::: "memory");  // tile kt landed (this wave's share)
      __syncthreads();  // all waves' shares visible; prior reads of slot cs^1 done
      if (kt + 1 < nkt) STAGEKV(cs ^ 1, kt + 1);

      if (kt * 64 <= qbase + 31) {  // wave has unmasked rows in this tile
        const char* Kbase = (const char*)&KV[cs][0][0];
        const char* Vbase = (const char*)&KV[cs][1][0];

        f32x4 s[2][4];
#pragma unroll
        for (int rf = 0; rf < 2; ++rf)
#pragma unroll
          for (int jt = 0; jt < 4; ++jt) s[rf][jt] = (f32x4){0.f, 0.f, 0.f, 0.f};
#pragma unroll
        for (int ks = 0; ks < 2; ++ks) {
          const int cbyte = ks ? cb1 : cb0;
#pragma unroll
          for (int jt = 0; jt < 4; ++jt) {
            bf16x8 kf = *(const bf16x8*)(Kbase + (jt * 16 + l15) * 128 + cbyte);
            s[0][jt] = __builtin_amdgcn_mfma_f32_16x16x32_bf16(kf, qf[0][ks], s[0][jt], 0, 0, 0);
            s[1][jt] = __builtin_amdgcn_mfma_f32_16x16x32_bf16(kf, qf[1][ks], s[1][jt], 0, 0, 0);
          }
        }

        if (kt * 64 + 63 > qbase) {  // diagonal-crossing: causal mask
#pragma unroll
          for (int rf = 0; rf < 2; ++rf) {
            int qg = qbase + rf * 16 + l15;
#pragma unroll
            for (int jt = 0; jt < 4; ++jt)
#pragma unroll
              for (int r = 0; r < 4; ++r) {
                int kg = kt * 64 + jt * 16 + lhi * 4 + r;
                if (kg > qg) s[rf][jt][r] = -1e30f;
              }
          }
        }

        // ---- row max (lane-local + 2 shfl), defer-max rescale (THR=8) ----
        float mr[2];
#pragma unroll
        for (int rf = 0; rf < 2; ++rf) {
          float v = fmaxf(fmaxf(s[rf][0][0], s[rf][0][1]), fmaxf(s[rf][0][2], s[rf][0][3]));
#pragma unroll
          for (int jt = 1; jt < 4; ++jt)
            v = fmaxf(v, fmaxf(fmaxf(s[rf][jt][0], s[rf][jt][1]),
                               fmaxf(s[rf][jt][2], s[rf][jt][3])));
          v = fmaxf(v, __shfl_xor(v, 16));
          v = fmaxf(v, __shfl_xor(v, 32));
          mr[rf] = v;
        }
        if (__any((mr[0] > m[0] + 8.f) || (mr[1] > m[1] + 8.f))) {
#pragma unroll
          for (int rf = 0; rf < 2; ++rf) {
            float mn = fmaxf(m[rf], mr[rf]);
            float sc = exp2f(m[rf] - mn);
            l[rf] *= sc;
            m[rf] = mn;
#pragma unroll
            for (int r = 0; r < 4; ++r) {
              float so = __shfl(sc, lhi * 4 + r);
#pragma unroll
              for (int f = 0; f < 4; ++f) o[rf][f][r] *= so;
            }
          }
        }

        // ---- exp2 + row sum ----
#pragma unroll
        for (int rf = 0; rf < 2; ++rf) {
          float rs = 0.f;
#pragma unroll
          for (int jt = 0; jt < 4; ++jt)
#pragma unroll
            for (int r = 0; r < 4; ++r) {
              float pv = exp2f(s[rf][jt][r] - m[rf]);
              s[rf][jt][r] = pv;
              rs += pv;
            }
          rs += __shfl_xor(rs, 16);
          rs += __shfl_xor(rs, 32);
          l[rf] += rs;
        }

        // ---- P -> bf16 via v_cvt_pk (T12), wave-private LDS, then PV ----
#pragma unroll
        for (int rf = 0; rf < 2; ++rf)
#pragma unroll
          for (int jt = 0; jt < 4; ++jt) {
            uint32_t lo, hi;
            asm("v_cvt_pk_bf16_f32 %0, %1, %2"
                : "=v"(lo) : "v"(s[rf][jt][0]), "v"(s[rf][jt][1]));
            asm("v_cvt_pk_bf16_f32 %0, %1, %2"
                : "=v"(hi) : "v"(s[rf][jt][2]), "v"(s[rf][jt][3]));
            uint2 pk; pk.x = lo; pk.y = hi;
            *(uint2*)&Ps[wv][(rf * 16 + l15) * 72 + jt * 16 + lhi * 4] = pk;
          }
#pragma unroll
        for (int ks = 0; ks < 2; ++ks) {
          const int cbyte = ks ? cb1 : cb0;
          bf16x8 pf0 = *(const bf16x8*)&Ps[wv][(l15)*72 + ks * 32 + lhi * 8];
          bf16x8 pf1 = *(const bf16x8*)&Ps[wv][(16 + l15) * 72 + ks * 32 + lhi * 8];
#pragma unroll
          for (int f = 0; f < 4; ++f) {
            bf16x8 vfr = *(const bf16x8*)(Vbase + (f * 16 + l15) * 128 + cbyte);
            o[0][f] = __builtin_amdgcn_mfma_f32_16x16x32_bf16(pf0, vfr, o[0][f], 0, 0, 0);
            o[1][f] = __builtin_amdgcn_mfma_f32_16x16x32_bf16(pf1, vfr, o[1][f], 0, 0, 0);
          }
        }
      }
    }

    // ---- epilogue ----
#pragma unroll
    for (int rf = 0; rf < 2; ++rf)
#pragma unroll
      for (int r = 0; r < 4; ++r) {
        float ld = __shfl(l[rf], lhi * 4 + r);
        float inv = 1.f / ld;
        int t = qbase + rf * 16 + lhi * 4 + r;
#pragma unroll
        for (int f = 0; f < 4; ++f)
          O[((size_t)(b * 2048 + t)) * 1024 + h * 64 + f * 16 + l15] = f2bf(o[rf][f][r] * inv);
      }
  }
#undef STAGEKV
}

extern "C" void kernel_launch(void* const* d_in, const int* in_sizes, int n_in,
                              void* d_out, int out_size, void* d_ws, size_t ws_size,
                              hipStream_t stream) {
  const float* x   = (const float*)d_in[0];
  const float* Wq  = (const float*)d_in[1];
  const float* Wk  = (const float*)d_in[2];
  const float* Wv  = (const float*)d_in[3];
  const float* Wo  = (const float*)d_in[4];
  const float* bo  = (const float*)d_in[5];
  const float* W1  = (const float*)d_in[6];
  const float* b1  = (const float*)d_in[7];
  const float* W2  = (const float*)d_in[8];
  const float* b2  = (const float*)d_in[9];
  const float* g1  = (const float*)d_in[10];
  const float* be1 = (const float*)d_in[11];
  const float* g2  = (const float*)d_in[12];
  const float* be2 = (const float*)d_in[13];

  char* p = (char*)d_ws;
  auto alloc = [&](size_t bytes) {
    char* r = p;
    p += (bytes + 255) & ~(size_t)255;
    return r;
  };
  u16* WqkvT = (u16*)alloc(3072ull * 1024 * 2);
  u16* WoT   = (u16*)alloc(1024ull * 1024 * 2);
  u16* W1T   = (u16*)alloc(4096ull * 1024 * 2);
  u16* W2T   = (u16*)alloc(1024ull * 4096 * 2);
  u16* hln   = (u16*)alloc(8192ull * 1024 * 2);
  u16* Qbuf  = (u16*)alloc(8192ull * 1024 * 2);
  u16* Kbuf  = (u16*)alloc(8192ull * 1024 * 2);
  u16* VTbuf = (u16*)alloc(8192ull * 1024 * 2);
  float* x2  = (float*)alloc(8192ull * 1024 * 4);
  u16* ff1   = (u16*)alloc(8192ull * 4096 * 2);
  u16* Oattn = hln;   // hln dead after QKV GEMM
  u16* h2    = Qbuf;  // Qbuf dead after attention
  if ((size_t)(p - (char*)d_ws) > ws_size) return;

  dim3 tb(32, 8);
  transpose_w<<<dim3(32, 32), tb, 0, stream>>>(Wq, WqkvT, 1024, 1024);
  transpose_w<<<dim3(32, 32), tb, 0, stream>>>(Wk, WqkvT + 1024 * 1024, 1024, 1024);
  transpose_w<<<dim3(32, 32), tb, 0, stream>>>(Wv, WqkvT + 2048 * 1024, 1024, 1024);
  transpose_w<<<dim3(32, 32), tb, 0, stream>>>(Wo, WoT, 1024, 1024);
  transpose_w<<<dim3(128, 32), tb, 0, stream>>>(W1, W1T, 1024, 4096);
  transpose_w<<<dim3(32, 128), tb, 0, stream>>>(W2, W2T, 4096, 1024);

  ln_kernel<<<8192, 256, 0, stream>>>(x, g1, be1, hln);

  gemm8p<0><<<dim3(24, 32), 512, 0, stream>>>(hln, WqkvT, 8192, 3072, 1024,
                                              nullptr, nullptr, nullptr,
                                              Qbuf, Kbuf, VTbuf);

  attn_kernel<<<dim3(8, 64), 256, 0, stream>>>(Qbuf, Kbuf, VTbuf, Oattn);

  gemm8p<1><<<dim3(8, 32), 512, 0, stream>>>(Oattn, WoT, 8192, 1024, 1024,
                                             bo, x, x2, nullptr, nullptr, nullptr);

  ln_kernel<<<8192, 256, 0, stream>>>(x2, g2, be2, h2);

  gemm8p<2><<<dim3(32, 32), 512, 0, stream>>>(h2, W1T, 8192, 4096, 1024,
                                              b1, nullptr, nullptr, ff1, nullptr, nullptr);

  gemm8p<3><<<dim3(8, 32), 512, 0, stream>>>(ff1, W2T, 8192, 1024, 4096,
                                             b2, x2, (float*)d_out, nullptr, nullptr, nullptr);
}

// Round 7
// 432.187 us; speedup vs baseline: 1.0340x; 1.0340x over previous
//
#include <hip/hip_runtime.h>
#include <cstdint>
#include <cstddef>

typedef unsigned short u16;
typedef __attribute__((ext_vector_type(8))) short bf16x8;
typedef __attribute__((ext_vector_type(4))) float f32x4;
typedef __attribute__((address_space(1))) const unsigned int gu32;
typedef __attribute__((address_space(3))) unsigned int lu32;

#define QSCALE 0.1803368801111204f  // 0.125 * log2(e): softmax done in exp2 domain

__device__ __forceinline__ u16 f2bf(float f) {
  uint32_t u = __float_as_uint(f);
  u += 0x7fffu + ((u >> 16) & 1u);
  return (u16)(u >> 16);
}

// ---------------- transpose fp32 (K,N) -> bf16 (N,K) ----------------
__global__ __launch_bounds__(256) void transpose_w(const float* __restrict__ W,
                                                   u16* __restrict__ WT,
                                                   int K, int N) {
  __shared__ float t[32][33];
  int n0 = blockIdx.x * 32, k0 = blockIdx.y * 32;
  for (int i = threadIdx.y; i < 32; i += 8)
    t[i][threadIdx.x] = W[(size_t)(k0 + i) * N + n0 + threadIdx.x];
  __syncthreads();
  for (int i = threadIdx.y; i < 32; i += 8)
    WT[(size_t)(n0 + i) * K + k0 + threadIdx.x] = f2bf(t[threadIdx.x][i]);
}

// ---------------- layernorm fp32 row(1024) -> bf16 ----------------
__global__ __launch_bounds__(256) void ln_kernel(const float* __restrict__ x,
                                                 const float* __restrict__ g,
                                                 const float* __restrict__ b,
                                                 u16* __restrict__ out) {
  int row = blockIdx.x;
  const float4 v = *(const float4*)(x + (size_t)row * 1024 + threadIdx.x * 4);
  float s = v.x + v.y + v.z + v.w;
  float ss = v.x * v.x + v.y * v.y + v.z * v.z + v.w * v.w;
#pragma unroll
  for (int d = 1; d < 64; d <<= 1) { s += __shfl_xor(s, d); ss += __shfl_xor(ss, d); }
  __shared__ float rs_[4], rss_[4];
  int wv = threadIdx.x >> 6;
  if ((threadIdx.x & 63) == 0) { rs_[wv] = s; rss_[wv] = ss; }
  __syncthreads();
  s = rs_[0] + rs_[1] + rs_[2] + rs_[3];
  ss = rss_[0] + rss_[1] + rss_[2] + rss_[3];
  float mu = s * (1.f / 1024.f);
  float var = ss * (1.f / 1024.f) - mu * mu;
  float rstd = rsqrtf(var + 1e-5f);
  float4 gv = *(const float4*)(g + threadIdx.x * 4);
  float4 bv = *(const float4*)(b + threadIdx.x * 4);
  uint32_t lo = (uint32_t)f2bf((v.x - mu) * rstd * gv.x + bv.x) |
                ((uint32_t)f2bf((v.y - mu) * rstd * gv.y + bv.y) << 16);
  uint32_t hi = (uint32_t)f2bf((v.z - mu) * rstd * gv.z + bv.z) |
                ((uint32_t)f2bf((v.w - mu) * rstd * gv.w + bv.w) << 16);
  uint2 o; o.x = lo; o.y = hi;
  *(uint2*)(out + (size_t)row * 1024 + threadIdx.x * 4) = o;
}

// ---------------- deep-pipelined GEMM: C = A(bf16 MxK) * BT(bf16 NxK) ----------------
// BM=256 BN=128 BK=64, 8 waves (4Mx2N), ring-3 LDS (144KB), prefetch 2 K-tiles ahead,
// counted vmcnt (6 steady), ks-OUTER MFMA order (dependent-reuse distance 8),
// T2 row-XOR swizzle, T5 setprio.
#define STAGEA(slot, tnext, is)                                               \
  __builtin_amdgcn_global_load_lds(                                           \
      (gu32*)((const char*)(A + (size_t)(bm * 256 + (is) * 64 + srow) * K +   \
                            (size_t)(tnext) * 64) + ssw),                     \
      (lu32*)&lds[(slot) * 24576 + (is) * 4096 + wid * 512], 16, 0, 0)
#define STAGEB(slot, tnext, is)                                               \
  __builtin_amdgcn_global_load_lds(                                           \
      (gu32*)((const char*)(BT + (size_t)(bn * 128 + (is) * 64 + srow) * K +  \
                            (size_t)(tnext) * 64) + ssw),                     \
      (lu32*)&lds[(slot) * 24576 + 16384 + (is) * 4096 + wid * 512], 16, 0, 0)

template <int MODE>
__global__ __launch_bounds__(512, 2) void gemm8p(
    const u16* __restrict__ A, const u16* __restrict__ BT,
    int M, int N, int K,
    const float* __restrict__ bias, const float* __restrict__ resid,
    float* __restrict__ outf,
    u16* __restrict__ ob0, u16* __restrict__ ob1, u16* __restrict__ ob2) {
  __shared__ __align__(16) u16 lds[73728];  // 3 x (A 256x64 + B 128x64) = 144 KB
  const int tid = threadIdx.x, lane = tid & 63, wid = tid >> 6;
  const int wr = wid >> 1, wc = wid & 1;
  const int bm = blockIdx.y, bn = blockIdx.x;
  const int l15 = lane & 15, lhi = lane >> 4;
  const int srow = tid >> 3;
  const int ssw = ((tid & 7) * 16) ^ ((srow & 7) << 4);
  const int cs0 = (lhi * 8) ^ ((l15 & 7) << 3);
  const int cs1 = (32 + lhi * 8) ^ ((l15 & 7) << 3);
  const int arow = (wr * 64 + l15) * 64;
  const int brow = (wc * 64 + l15) * 64;

  f32x4 acc[4][4];
#pragma unroll
  for (int i = 0; i < 4; ++i)
#pragma unroll
    for (int j = 0; j < 4; ++j) acc[i][j] = (f32x4){0.f, 0.f, 0.f, 0.f};

  const int NT = K >> 6;

  // prologue: stage tiles 0,1 into slots 0,1 (loop stages tile 2 at t=0)
#pragma unroll
  for (int t0 = 0; t0 < 2; ++t0) {
    STAGEA(t0, t0, 0); STAGEA(t0, t0, 1); STAGEA(t0, t0, 2); STAGEA(t0, t0, 3);
    STAGEB(t0, t0, 0); STAGEB(t0, t0, 1);
  }
  asm volatile("s_waitcnt vmcnt(6)" ::: "memory");  // tile 0 landed
  __builtin_amdgcn_s_barrier();

  int s = 0, sn = 2;
  for (int t = 0; t < NT; ++t) {
    const bool hasPre = (t + 2) < NT;
    const int aoff = s * 24576, boff = s * 24576 + 16384;

    bf16x8 bfr[4][2], afr[2][2];
#pragma unroll
    for (int ni = 0; ni < 4; ++ni) {
      bfr[ni][0] = *(const bf16x8*)&lds[boff + brow + ni * 1024 + cs0];
      bfr[ni][1] = *(const bf16x8*)&lds[boff + brow + ni * 1024 + cs1];
    }
    afr[0][0] = *(const bf16x8*)&lds[aoff + arow + cs0];
    afr[0][1] = *(const bf16x8*)&lds[aoff + arow + cs1];
    afr[1][0] = *(const bf16x8*)&lds[aoff + arow + 1024 + cs0];
    afr[1][1] = *(const bf16x8*)&lds[aoff + arow + 1024 + cs1];
    if (hasPre) { STAGEA(sn, t + 2, 0); STAGEA(sn, t + 2, 1); STAGEB(sn, t + 2, 0); }
    __builtin_amdgcn_s_barrier();
    __builtin_amdgcn_s_setprio(1);
#pragma unroll
    for (int ks = 0; ks < 2; ++ks)
#pragma unroll
      for (int ml = 0; ml < 2; ++ml)
#pragma unroll
        for (int ni = 0; ni < 4; ++ni)
          acc[ml][ni] = __builtin_amdgcn_mfma_f32_16x16x32_bf16(afr[ml][ks], bfr[ni][ks], acc[ml][ni], 0, 0, 0);
    __builtin_amdgcn_s_setprio(0);
    __builtin_amdgcn_s_barrier();

    afr[0][0] = *(const bf16x8*)&lds[aoff + arow + 2048 + cs0];
    afr[0][1] = *(const bf16x8*)&lds[aoff + arow + 2048 + cs1];
    afr[1][0] = *(const bf16x8*)&lds[aoff + arow + 3072 + cs0];
    afr[1][1] = *(const bf16x8*)&lds[aoff + arow + 3072 + cs1];
    if (hasPre) { STAGEA(sn, t + 2, 2); STAGEA(sn, t + 2, 3); STAGEB(sn, t + 2, 1); }
    __builtin_amdgcn_s_barrier();
    __builtin_amdgcn_s_setprio(1);
#pragma unroll
    for (int ks = 0; ks < 2; ++ks)
#pragma unroll
      for (int ml = 0; ml < 2; ++ml)
#pragma unroll
        for (int ni = 0; ni < 4; ++ni)
          acc[2 + ml][ni] = __builtin_amdgcn_mfma_f32_16x16x32_bf16(afr[ml][ks], bfr[ni][ks], acc[2 + ml][ni], 0, 0, 0);
    __builtin_amdgcn_s_setprio(0);
    if (hasPre) {
      asm volatile("s_waitcnt vmcnt(6)" ::: "memory");
    } else if (t + 1 < NT) {
      asm volatile("s_waitcnt vmcnt(0)" ::: "memory");
    }
    __builtin_amdgcn_s_barrier();

    s = (s == 2) ? 0 : s + 1;
    sn = (sn == 2) ? 0 : sn + 1;
  }

#pragma unroll
  for (int mi = 0; mi < 4; ++mi) {
#pragma unroll
    for (int ni = 0; ni < 4; ++ni) {
      int col = bn * 128 + wc * 64 + ni * 16 + l15;
      int rbase = bm * 256 + wr * 64 + mi * 16 + lhi * 4;
#pragma unroll
      for (int r = 0; r < 4; ++r) {
        float v = acc[mi][ni][r];
        int rg = rbase + r;
        if (MODE == 0) {
          int b = rg >> 11, tt = rg & 2047;
          int cm = col & 1023, h = cm >> 6, d = cm & 63;
          size_t bh = (size_t)(b * 16 + h);
          if (col < 1024)
            ob0[(bh * 2048 + tt) * 64 + d] = f2bf(v * QSCALE);
          else if (col < 2048)
            ob1[(bh * 2048 + tt) * 64 + d] = f2bf(v);
          else
            ob2[(bh * 64 + d) * 2048 + tt] = f2bf(v);
        } else if (MODE == 1) {
          outf[(size_t)rg * N + col] = v + bias[col] + resid[(size_t)rg * N + col];
        } else if (MODE == 2) {
          ob0[(size_t)rg * N + col] = f2bf(fmaxf(v + bias[col], 0.f));
        } else {
          outf[(size_t)rg * N + col] = fmaxf(v + bias[col], 0.f) + resid[(size_t)rg * N + col];
        }
      }
    }
  }
}

// ---------------- causal flash attention ----------------
// 8 waves x 16 q-rows = 128-row chunk per block; chunk pairing (15-p, p) over 16
// chunks -> 512 blocks x 8 waves = 16 waves/CU (2 blocks/CU, 50KB LDS each).
// Swapped QK^T in exp2 domain, global_load_lds K/V staging (XOR swizzle, dbuf),
// defer-max (THR=8), cvt_pk P-pack, setprio on MFMA clusters.
__global__ __launch_bounds__(512) void attn_kernel(
    const u16* __restrict__ Qb, const u16* __restrict__ Kb,
    const u16* __restrict__ VTb, u16* __restrict__ O) {
  const int p = blockIdx.x;  // 0..7
  const int bh = blockIdx.y;
  const u16* Q = Qb + (size_t)bh * 2048 * 64;
  const u16* Kp = Kb + (size_t)bh * 2048 * 64;
  const u16* VT = VTb + (size_t)bh * 64 * 2048;
  const int tid = threadIdx.x, lane = tid & 63, wv = tid >> 6;
  const int l15 = lane & 15, lhi = lane >> 4;
  const int srow = tid >> 3;             // 0..63
  const int scol16 = (tid & 7) * 16;     // byte within 128B row
  const int sw = scol16 ^ ((srow & 7) << 4);  // inverse-swizzled src byte
  const int rswz = (l15 & 7) << 4;
  const int cb0 = (lhi * 16) ^ rswz;     // swizzled byte col, ks=0
  const int cb1 = (64 + lhi * 16) ^ rswz;
  const int b = bh >> 4, h = bh & 15;

  __shared__ __align__(16) u16 KV[2][2][4096];  // [slot][K,V][64x64] = 32 KB
  __shared__ u16 Ps[8][16 * 72];                // 18 KB

#define STAGEKV(slot, kt)                                                     \
  do {                                                                        \
    __builtin_amdgcn_global_load_lds(                                         \
        (gu32*)((const char*)(Kp + (size_t)((kt)*64 + srow) * 64) + sw),      \
        (lu32*)&KV[slot][0][wv * 512], 16, 0, 0);                             \
    __builtin_amdgcn_global_load_lds(                                         \
        (gu32*)((const char*)(VT + (size_t)srow * 2048 + (kt)*64) + sw),      \
        (lu32*)&KV[slot][1][wv * 512], 16, 0, 0);                             \
  } while (0)

#pragma unroll
  for (int pass = 0; pass < 2; ++pass) {
    const int chunk = pass ? p : (15 - p);
    const int qbase = chunk * 128 + wv * 16;
    const int nkt = 2 * chunk + 2;

    bf16x8 qf[2];
#pragma unroll
    for (int ks = 0; ks < 2; ++ks)
      qf[ks] = *(const bf16x8*)&Q[(size_t)(qbase + l15) * 64 + ks * 32 + lhi * 8];

    f32x4 o[4];
#pragma unroll
    for (int f = 0; f < 4; ++f) o[f] = (f32x4){0.f, 0.f, 0.f, 0.f};
    float m = -1e30f;
    float l = 0.f;

    __syncthreads();  // prior pass's LDS reads complete across all waves
    STAGEKV(0, 0);

    for (int kt = 0; kt < nkt; ++kt) {
      const int cs = kt & 1;
      asm volatile("s_waitcnt vmcnt(0)" ::: "memory");  // tile kt landed (this thread's share)
      __syncthreads();  // all threads' shares visible; prior reads of slot cs^1 done
      if (kt + 1 < nkt) STAGEKV(cs ^ 1, kt + 1);

      if (kt * 64 <= qbase + 15) {  // wave has unmasked rows in this tile
        const char* Kbase = (const char*)&KV[cs][0][0];
        const char* Vbase = (const char*)&KV[cs][1][0];

        f32x4 s[4];
#pragma unroll
        for (int jt = 0; jt < 4; ++jt) s[jt] = (f32x4){0.f, 0.f, 0.f, 0.f};
        __builtin_amdgcn_s_setprio(1);
#pragma unroll
        for (int ks = 0; ks < 2; ++ks) {
          const int cbyte = ks ? cb1 : cb0;
#pragma unroll
          for (int jt = 0; jt < 4; ++jt) {
            bf16x8 kf = *(const bf16x8*)(Kbase + (jt * 16 + l15) * 128 + cbyte);
            s[jt] = __builtin_amdgcn_mfma_f32_16x16x32_bf16(kf, qf[ks], s[jt], 0, 0, 0);
          }
        }
        __builtin_amdgcn_s_setprio(0);

        if (kt * 64 + 63 > qbase) {  // diagonal-crossing: causal mask
          int qg = qbase + l15;
#pragma unroll
          for (int jt = 0; jt < 4; ++jt)
#pragma unroll
            for (int r = 0; r < 4; ++r) {
              int kg = kt * 64 + jt * 16 + lhi * 4 + r;
              if (kg > qg) s[jt][r] = -1e30f;
            }
        }

        // ---- row max (lane-local + 2 shfl), defer-max rescale (THR=8) ----
        float mr = fmaxf(fmaxf(s[0][0], s[0][1]), fmaxf(s[0][2], s[0][3]));
#pragma unroll
        for (int jt = 1; jt < 4; ++jt)
          mr = fmaxf(mr, fmaxf(fmaxf(s[jt][0], s[jt][1]), fmaxf(s[jt][2], s[jt][3])));
        mr = fmaxf(mr, __shfl_xor(mr, 16));
        mr = fmaxf(mr, __shfl_xor(mr, 32));
        if (__any(mr > m + 8.f)) {
          float mn = fmaxf(m, mr);
          float sc = exp2f(m - mn);
          l *= sc;
          m = mn;
#pragma unroll
          for (int r = 0; r < 4; ++r) {
            float so = __shfl(sc, lhi * 4 + r);
#pragma unroll
            for (int f = 0; f < 4; ++f) o[f][r] *= so;
          }
        }

        // ---- exp2 + row sum ----
        float rs = 0.f;
#pragma unroll
        for (int jt = 0; jt < 4; ++jt)
#pragma unroll
          for (int r = 0; r < 4; ++r) {
            float pv = exp2f(s[jt][r] - m);
            s[jt][r] = pv;
            rs += pv;
          }
        rs += __shfl_xor(rs, 16);
        rs += __shfl_xor(rs, 32);
        l += rs;

        // ---- P -> bf16 via v_cvt_pk (T12), wave-private LDS, then PV ----
#pragma unroll
        for (int jt = 0; jt < 4; ++jt) {
          uint32_t lo, hi;
          asm("v_cvt_pk_bf16_f32 %0, %1, %2"
              : "=v"(lo) : "v"(s[jt][0]), "v"(s[jt][1]));
          asm("v_cvt_pk_bf16_f32 %0, %1, %2"
              : "=v"(hi) : "v"(s[jt][2]), "v"(s[jt][3]));
          uint2 pk; pk.x = lo; pk.y = hi;
          *(uint2*)&Ps[wv][l15 * 72 + jt * 16 + lhi * 4] = pk;
        }
        __builtin_amdgcn_s_setprio(1);
#pragma unroll
        for (int ks = 0; ks < 2; ++ks) {
          const int cbyte = ks ? cb1 : cb0;
          bf16x8 pf = *(const bf16x8*)&Ps[wv][l15 * 72 + ks * 32 + lhi * 8];
#pragma unroll
          for (int f = 0; f < 4; ++f) {
            bf16x8 vfr = *(const bf16x8*)(Vbase + (f * 16 + l15) * 128 + cbyte);
            o[f] = __builtin_amdgcn_mfma_f32_16x16x32_bf16(pf, vfr, o[f], 0, 0, 0);
          }
        }
        __builtin_amdgcn_s_setprio(0);
      }
    }

    // ---- epilogue ----
#pragma unroll
    for (int r = 0; r < 4; ++r) {
      float ld = __shfl(l, lhi * 4 + r);
      float inv = 1.f / ld;
      int t = qbase + lhi * 4 + r;
#pragma unroll
      for (int f = 0; f < 4; ++f)
        O[((size_t)(b * 2048 + t)) * 1024 + h * 64 + f * 16 + l15] = f2bf(o[f][r] * inv);
    }
  }
#undef STAGEKV
}

extern "C" void kernel_launch(void* const* d_in, const int* in_sizes, int n_in,
                              void* d_out, int out_size, void* d_ws, size_t ws_size,
                              hipStream_t stream) {
  const float* x   = (const float*)d_in[0];
  const float* Wq  = (const float*)d_in[1];
  const float* Wk  = (const float*)d_in[2];
  const float* Wv  = (const float*)d_in[3];
  const float* Wo  = (const float*)d_in[4];
  const float* bo  = (const float*)d_in[5];
  const float* W1  = (const float*)d_in[6];
  const float* b1  = (const float*)d_in[7];
  const float* W2  = (const float*)d_in[8];
  const float* b2  = (const float*)d_in[9];
  const float* g1  = (const float*)d_in[10];
  const float* be1 = (const float*)d_in[11];
  const float* g2  = (const float*)d_in[12];
  const float* be2 = (const float*)d_in[13];

  char* p = (char*)d_ws;
  auto alloc = [&](size_t bytes) {
    char* r = p;
    p += (bytes + 255) & ~(size_t)255;
    return r;
  };
  u16* WqkvT = (u16*)alloc(3072ull * 1024 * 2);
  u16* WoT   = (u16*)alloc(1024ull * 1024 * 2);
  u16* W1T   = (u16*)alloc(4096ull * 1024 * 2);
  u16* W2T   = (u16*)alloc(1024ull * 4096 * 2);
  u16* hln   = (u16*)alloc(8192ull * 1024 * 2);
  u16* Qbuf  = (u16*)alloc(8192ull * 1024 * 2);
  u16* Kbuf  = (u16*)alloc(8192ull * 1024 * 2);
  u16* VTbuf = (u16*)alloc(8192ull * 1024 * 2);
  float* x2  = (float*)alloc(8192ull * 1024 * 4);
  u16* ff1   = (u16*)alloc(8192ull * 4096 * 2);
  u16* Oattn = hln;   // hln dead after QKV GEMM
  u16* h2    = Qbuf;  // Qbuf dead after attention
  if ((size_t)(p - (char*)d_ws) > ws_size) return;

  dim3 tb(32, 8);
  transpose_w<<<dim3(32, 32), tb, 0, stream>>>(Wq, WqkvT, 1024, 1024);
  transpose_w<<<dim3(32, 32), tb, 0, stream>>>(Wk, WqkvT + 1024 * 1024, 1024, 1024);
  transpose_w<<<dim3(32, 32), tb, 0, stream>>>(Wv, WqkvT + 2048 * 1024, 1024, 1024);
  transpose_w<<<dim3(32, 32), tb, 0, stream>>>(Wo, WoT, 1024, 1024);
  transpose_w<<<dim3(128, 32), tb, 0, stream>>>(W1, W1T, 1024, 4096);
  transpose_w<<<dim3(32, 128), tb, 0, stream>>>(W2, W2T, 4096, 1024);

  ln_kernel<<<8192, 256, 0, stream>>>(x, g1, be1, hln);

  gemm8p<0><<<dim3(24, 32), 512, 0, stream>>>(hln, WqkvT, 8192, 3072, 1024,
                                              nullptr, nullptr, nullptr,
                                              Qbuf, Kbuf, VTbuf);

  attn_kernel<<<dim3(8, 64), 512, 0, stream>>>(Qbuf, Kbuf, VTbuf, Oattn);

  gemm8p<1><<<dim3(8, 32), 512, 0, stream>>>(Oattn, WoT, 8192, 1024, 1024,
                                             bo, x, x2, nullptr, nullptr, nullptr);

  ln_kernel<<<8192, 256, 0, stream>>>(x2, g2, be2, h2);

  gemm8p<2><<<dim3(32, 32), 512, 0, stream>>>(h2, W1T, 8192, 4096, 1024,
                                              b1, nullptr, nullptr, ff1, nullptr, nullptr);

  gemm8p<3><<<dim3(8, 32), 512, 0, stream>>>(ff1, W2T, 8192, 1024, 4096,
                                             b2, x2, (float*)d_out, nullptr, nullptr, nullptr);
}

// Round 8
// 403.881 us; speedup vs baseline: 1.1064x; 1.0701x over previous
//
#include <hip/hip_runtime.h>
#include <cstdint>
#include <cstddef>

typedef unsigned short u16;
typedef __attribute__((ext_vector_type(8))) short bf16x8;
typedef __attribute__((ext_vector_type(4))) float f32x4;
typedef __attribute__((address_space(1))) const unsigned int gu32;
typedef __attribute__((address_space(3))) unsigned int lu32;

#define QSCALE 0.1803368801111204f  // 0.125 * log2(e): softmax done in exp2 domain

__device__ __forceinline__ u16 f2bf(float f) {
  uint32_t u = __float_as_uint(f);
  u += 0x7fffu + ((u >> 16) & 1u);
  return (u16)(u >> 16);
}

// ---------------- transpose fp32 (K,N) -> bf16 (N,K) ----------------
__global__ __launch_bounds__(256) void transpose_w(const float* __restrict__ W,
                                                   u16* __restrict__ WT,
                                                   int K, int N) {
  __shared__ float t[32][33];
  int n0 = blockIdx.x * 32, k0 = blockIdx.y * 32;
  for (int i = threadIdx.y; i < 32; i += 8)
    t[i][threadIdx.x] = W[(size_t)(k0 + i) * N + n0 + threadIdx.x];
  __syncthreads();
  for (int i = threadIdx.y; i < 32; i += 8)
    WT[(size_t)(n0 + i) * K + k0 + threadIdx.x] = f2bf(t[threadIdx.x][i]);
}

// ---------------- layernorm fp32 row(1024) -> bf16 ----------------
__global__ __launch_bounds__(256) void ln_kernel(const float* __restrict__ x,
                                                 const float* __restrict__ g,
                                                 const float* __restrict__ b,
                                                 u16* __restrict__ out) {
  int row = blockIdx.x;
  const float4 v = *(const float4*)(x + (size_t)row * 1024 + threadIdx.x * 4);
  float s = v.x + v.y + v.z + v.w;
  float ss = v.x * v.x + v.y * v.y + v.z * v.z + v.w * v.w;
#pragma unroll
  for (int d = 1; d < 64; d <<= 1) { s += __shfl_xor(s, d); ss += __shfl_xor(ss, d); }
  __shared__ float rs_[4], rss_[4];
  int wv = threadIdx.x >> 6;
  if ((threadIdx.x & 63) == 0) { rs_[wv] = s; rss_[wv] = ss; }
  __syncthreads();
  s = rs_[0] + rs_[1] + rs_[2] + rs_[3];
  ss = rss_[0] + rss_[1] + rss_[2] + rss_[3];
  float mu = s * (1.f / 1024.f);
  float var = ss * (1.f / 1024.f) - mu * mu;
  float rstd = rsqrtf(var + 1e-5f);
  float4 gv = *(const float4*)(g + threadIdx.x * 4);
  float4 bv = *(const float4*)(b + threadIdx.x * 4);
  uint32_t lo = (uint32_t)f2bf((v.x - mu) * rstd * gv.x + bv.x) |
                ((uint32_t)f2bf((v.y - mu) * rstd * gv.y + bv.y) << 16);
  uint32_t hi = (uint32_t)f2bf((v.z - mu) * rstd * gv.z + bv.z) |
                ((uint32_t)f2bf((v.w - mu) * rstd * gv.w + bv.w) << 16);
  uint2 o; o.x = lo; o.y = hi;
  *(uint2*)(out + (size_t)row * 1024 + threadIdx.x * 4) = o;
}

// ---------------- deep-pipelined GEMM: C = A(bf16 MxK) * BT(bf16 NxK) ----------------
// BM=256 BN=128 BK=64, 8 waves (4Mx2N), ring-3 LDS (144KB), prefetch 2 K-tiles ahead,
// counted vmcnt (6 steady), ks-OUTER MFMA order, T2 row-XOR swizzle, T5 setprio.
// LDS-staged coalesced epilogue for bf16 outputs (MODE 0/2).
// MODE 0: QKV (N=3072) -> Q2[B,T,1024]*QSCALE / K2[B,T,1024] / VT[B,H,HD,T]
// MODE 1: PROJ -> outf = acc + bias + resid      (fp32)
// MODE 2: FF1  -> ob0  = bf16(relu(acc + bias))  (row-major, LDS epilogue)
// MODE 3: FF2  -> outf = relu(acc + bias) + resid (fp32)
#define STAGEA(slot, tnext, is)                                               \
  __builtin_amdgcn_global_load_lds(                                           \
      (gu32*)((const char*)(A + (size_t)(bm * 256 + (is) * 64 + srow) * K +   \
                            (size_t)(tnext) * 64) + ssw),                     \
      (lu32*)&lds[(slot) * 24576 + (is) * 4096 + wid * 512], 16, 0, 0)
#define STAGEB(slot, tnext, is)                                               \
  __builtin_amdgcn_global_load_lds(                                           \
      (gu32*)((const char*)(BT + (size_t)(bn * 128 + (is) * 64 + srow) * K +  \
                            (size_t)(tnext) * 64) + ssw),                     \
      (lu32*)&lds[(slot) * 24576 + 16384 + (is) * 4096 + wid * 512], 16, 0, 0)

template <int MODE>
__global__ __launch_bounds__(512, 2) void gemm8p(
    const u16* __restrict__ A, const u16* __restrict__ BT,
    int M, int N, int K,
    const float* __restrict__ bias, const float* __restrict__ resid,
    float* __restrict__ outf,
    u16* __restrict__ ob0, u16* __restrict__ ob1, u16* __restrict__ ob2) {
  __shared__ __align__(16) u16 lds[73728];  // 3 x (A 256x64 + B 128x64) = 144 KB
  const int tid = threadIdx.x, lane = tid & 63, wid = tid >> 6;
  const int wr = wid >> 1, wc = wid & 1;
  const int bm = blockIdx.y, bn = blockIdx.x;
  const int l15 = lane & 15, lhi = lane >> 4;
  const int srow = tid >> 3;
  const int ssw = ((tid & 7) * 16) ^ ((srow & 7) << 4);
  const int cs0 = (lhi * 8) ^ ((l15 & 7) << 3);
  const int cs1 = (32 + lhi * 8) ^ ((l15 & 7) << 3);
  const int arow = (wr * 64 + l15) * 64;
  const int brow = (wc * 64 + l15) * 64;

  f32x4 acc[4][4];
#pragma unroll
  for (int i = 0; i < 4; ++i)
#pragma unroll
    for (int j = 0; j < 4; ++j) acc[i][j] = (f32x4){0.f, 0.f, 0.f, 0.f};

  const int NT = K >> 6;

  // prologue: stage tiles 0,1 into slots 0,1 (loop stages tile 2 at t=0)
#pragma unroll
  for (int t0 = 0; t0 < 2; ++t0) {
    STAGEA(t0, t0, 0); STAGEA(t0, t0, 1); STAGEA(t0, t0, 2); STAGEA(t0, t0, 3);
    STAGEB(t0, t0, 0); STAGEB(t0, t0, 1);
  }
  asm volatile("s_waitcnt vmcnt(6)" ::: "memory");  // tile 0 landed
  __builtin_amdgcn_s_barrier();

  int s = 0, sn = 2;
  for (int t = 0; t < NT; ++t) {
    const bool hasPre = (t + 2) < NT;
    const int aoff = s * 24576, boff = s * 24576 + 16384;

    bf16x8 bfr[4][2], afr[2][2];
#pragma unroll
    for (int ni = 0; ni < 4; ++ni) {
      bfr[ni][0] = *(const bf16x8*)&lds[boff + brow + ni * 1024 + cs0];
      bfr[ni][1] = *(const bf16x8*)&lds[boff + brow + ni * 1024 + cs1];
    }
    afr[0][0] = *(const bf16x8*)&lds[aoff + arow + cs0];
    afr[0][1] = *(const bf16x8*)&lds[aoff + arow + cs1];
    afr[1][0] = *(const bf16x8*)&lds[aoff + arow + 1024 + cs0];
    afr[1][1] = *(const bf16x8*)&lds[aoff + arow + 1024 + cs1];
    if (hasPre) { STAGEA(sn, t + 2, 0); STAGEA(sn, t + 2, 1); STAGEB(sn, t + 2, 0); }
    __builtin_amdgcn_s_barrier();
    __builtin_amdgcn_s_setprio(1);
#pragma unroll
    for (int ks = 0; ks < 2; ++ks)
#pragma unroll
      for (int ml = 0; ml < 2; ++ml)
#pragma unroll
        for (int ni = 0; ni < 4; ++ni)
          acc[ml][ni] = __builtin_amdgcn_mfma_f32_16x16x32_bf16(afr[ml][ks], bfr[ni][ks], acc[ml][ni], 0, 0, 0);
    __builtin_amdgcn_s_setprio(0);
    __builtin_amdgcn_s_barrier();

    afr[0][0] = *(const bf16x8*)&lds[aoff + arow + 2048 + cs0];
    afr[0][1] = *(const bf16x8*)&lds[aoff + arow + 2048 + cs1];
    afr[1][0] = *(const bf16x8*)&lds[aoff + arow + 3072 + cs0];
    afr[1][1] = *(const bf16x8*)&lds[aoff + arow + 3072 + cs1];
    if (hasPre) { STAGEA(sn, t + 2, 2); STAGEA(sn, t + 2, 3); STAGEB(sn, t + 2, 1); }
    __builtin_amdgcn_s_barrier();
    __builtin_amdgcn_s_setprio(1);
#pragma unroll
    for (int ks = 0; ks < 2; ++ks)
#pragma unroll
      for (int ml = 0; ml < 2; ++ml)
#pragma unroll
        for (int ni = 0; ni < 4; ++ni)
          acc[2 + ml][ni] = __builtin_amdgcn_mfma_f32_16x16x32_bf16(afr[ml][ks], bfr[ni][ks], acc[2 + ml][ni], 0, 0, 0);
    __builtin_amdgcn_s_setprio(0);
    if (hasPre) {
      asm volatile("s_waitcnt vmcnt(6)" ::: "memory");
    } else if (t + 1 < NT) {
      asm volatile("s_waitcnt vmcnt(0)" ::: "memory");
    }
    __builtin_amdgcn_s_barrier();

    s = (s == 2) ? 0 : s + 1;
    sn = (sn == 2) ? 0 : sn + 1;
  }

  // ---------------- epilogue ----------------
  if (MODE == 0 || MODE == 2) {
    // LDS-staged coalesced epilogue (all waves past final barrier; LDS free)
    char* ep = (char*)lds;
    const bool vmode = (MODE == 0) && (bn >= 16);
    if (vmode) {
      // V part: LDS [128 col][264 u16 pitch], b64-packed r-quads -> VT rows
#pragma unroll
      for (int mi = 0; mi < 4; ++mi)
#pragma unroll
        for (int ni = 0; ni < 4; ++ni) {
          uint32_t lo, hi;
          asm("v_cvt_pk_bf16_f32 %0, %1, %2"
              : "=v"(lo) : "v"(acc[mi][ni][0]), "v"(acc[mi][ni][1]));
          asm("v_cvt_pk_bf16_f32 %0, %1, %2"
              : "=v"(hi) : "v"(acc[mi][ni][2]), "v"(acc[mi][ni][3]));
          uint2 pk; pk.x = lo; pk.y = hi;
          int c_local = wc * 64 + ni * 16 + l15;
          int rb = wr * 64 + mi * 16 + lhi * 4;
          *(uint2*)(ep + c_local * 528 + rb * 2) = pk;
        }
    } else {
      // Q/K/FF1: LDS [256 row][136 u16 pitch], scalar b16 writes
      const float sc = (MODE == 0 && bn < 8) ? QSCALE : 1.f;
#pragma unroll
      for (int mi = 0; mi < 4; ++mi)
#pragma unroll
        for (int ni = 0; ni < 4; ++ni) {
          int c_local = wc * 64 + ni * 16 + l15;
          int rb = wr * 64 + mi * 16 + lhi * 4;
          float bv = (MODE == 2) ? bias[bn * 128 + c_local] : 0.f;
#pragma unroll
          for (int r = 0; r < 4; ++r) {
            float v = acc[mi][ni][r];
            if (MODE == 2) v = fmaxf(v + bv, 0.f);
            else v *= sc;
            *(u16*)(ep + (rb + r) * 272 + c_local * 2) = f2bf(v);
          }
        }
    }
    __syncthreads();
    if (vmode) {
#pragma unroll
      for (int i = 0; i < 8; ++i) {
        int idx = i * 512 + tid;
        int c = idx >> 5, tc = idx & 31;
        uint4 d4 = *(const uint4*)(ep + c * 528 + tc * 16);
        int cm = bn * 128 + c - 2048, hh = cm >> 6, dd = cm & 63;
        size_t bh = (size_t)((bm >> 3) * 16 + hh);
        int t0 = (bm & 7) * 256;
        *(uint4*)&ob2[(bh * 64 + dd) * 2048 + t0 + tc * 8] = d4;
      }
    } else {
#pragma unroll
      for (int i = 0; i < 8; ++i) {
        int idx = i * 512 + tid;
        int row = idx >> 4, cc = idx & 15;
        uint4 d4 = *(const uint4*)(ep + row * 272 + cc * 16);
        size_t rg = (size_t)(bm * 256 + row);
        if (MODE == 2) {
          *(uint4*)&ob0[rg * N + bn * 128 + cc * 8] = d4;
        } else {
          int colg = bn * 128 + cc * 8;
          if (colg < 1024)
            *(uint4*)&ob0[rg * 1024 + colg] = d4;       // Q2 (pre-scaled)
          else
            *(uint4*)&ob1[rg * 1024 + colg - 1024] = d4; // K2
        }
      }
    }
  } else {
#pragma unroll
    for (int mi = 0; mi < 4; ++mi) {
#pragma unroll
      for (int ni = 0; ni < 4; ++ni) {
        int col = bn * 128 + wc * 64 + ni * 16 + l15;
        int rbase = bm * 256 + wr * 64 + mi * 16 + lhi * 4;
#pragma unroll
        for (int r = 0; r < 4; ++r) {
          float v = acc[mi][ni][r];
          int rg = rbase + r;
          if (MODE == 1) {
            outf[(size_t)rg * N + col] = v + bias[col] + resid[(size_t)rg * N + col];
          } else {
            outf[(size_t)rg * N + col] = fmaxf(v + bias[col], 0.f) + resid[(size_t)rg * N + col];
          }
        }
      }
    }
  }
}

// ---------------- causal flash attention ----------------
// 8 waves x 16 q-rows; chunk pairing (15-p, p); Q2/K2 in natural [B,T,1024] layout,
// VT [B,H,HD,T]. Swapped QK^T in exp2 domain, global_load_lds K/V staging
// (XOR swizzle, dbuf), defer-max, cvt_pk P-pack, setprio on MFMA clusters.
__global__ __launch_bounds__(512) void attn_kernel(
    const u16* __restrict__ Qb, const u16* __restrict__ Kb,
    const u16* __restrict__ VTb, u16* __restrict__ O) {
  const int p = blockIdx.x;  // 0..7
  const int bh = blockIdx.y;
  const int b = bh >> 4, h = bh & 15;
  const u16* Q = Qb + (size_t)b * 2048 * 1024 + h * 64;   // natural layout
  const u16* Kn = Kb + (size_t)b * 2048 * 1024 + h * 64;
  const u16* VT = VTb + (size_t)bh * 64 * 2048;
  const int tid = threadIdx.x, lane = tid & 63, wv = tid >> 6;
  const int l15 = lane & 15, lhi = lane >> 4;
  const int srow = tid >> 3;             // 0..63
  const int scol16 = (tid & 7) * 16;     // byte within 128B row
  const int sw = scol16 ^ ((srow & 7) << 4);  // inverse-swizzled src byte
  const int rswz = (l15 & 7) << 4;
  const int cb0 = (lhi * 16) ^ rswz;     // swizzled byte col, ks=0
  const int cb1 = (64 + lhi * 16) ^ rswz;

  __shared__ __align__(16) u16 KV[2][2][4096];  // [slot][K,V][64x64] = 32 KB
  __shared__ u16 Ps[8][16 * 72];                // 18 KB

#define STAGEKV(slot, kt)                                                     \
  do {                                                                        \
    __builtin_amdgcn_global_load_lds(                                         \
        (gu32*)((const char*)(Kn + (size_t)((kt)*64 + srow) * 1024) + sw),    \
        (lu32*)&KV[slot][0][wv * 512], 16, 0, 0);                             \
    __builtin_amdgcn_global_load_lds(                                         \
        (gu32*)((const char*)(VT + (size_t)srow * 2048 + (kt)*64) + sw),      \
        (lu32*)&KV[slot][1][wv * 512], 16, 0, 0);                             \
  } while (0)

#pragma unroll
  for (int pass = 0; pass < 2; ++pass) {
    const int chunk = pass ? p : (15 - p);
    const int qbase = chunk * 128 + wv * 16;
    const int nkt = 2 * chunk + 2;

    bf16x8 qf[2];
#pragma unroll
    for (int ks = 0; ks < 2; ++ks)
      qf[ks] = *(const bf16x8*)&Q[(size_t)(qbase + l15) * 1024 + ks * 32 + lhi * 8];

    f32x4 o[4];
#pragma unroll
    for (int f = 0; f < 4; ++f) o[f] = (f32x4){0.f, 0.f, 0.f, 0.f};
    float m = -1e30f;
    float l = 0.f;

    __syncthreads();  // prior pass's LDS reads complete across all waves
    STAGEKV(0, 0);

    for (int kt = 0; kt < nkt; ++kt) {
      const int cs = kt & 1;
      asm volatile("s_waitcnt vmcnt(0)" ::: "memory");
      __syncthreads();
      if (kt + 1 < nkt) STAGEKV(cs ^ 1, kt + 1);

      if (kt * 64 <= qbase + 15) {
        const char* Kbase = (const char*)&KV[cs][0][0];
        const char* Vbase = (const char*)&KV[cs][1][0];

        f32x4 s[4];
#pragma unroll
        for (int jt = 0; jt < 4; ++jt) s[jt] = (f32x4){0.f, 0.f, 0.f, 0.f};
        __builtin_amdgcn_s_setprio(1);
#pragma unroll
        for (int ks = 0; ks < 2; ++ks) {
          const int cbyte = ks ? cb1 : cb0;
#pragma unroll
          for (int jt = 0; jt < 4; ++jt) {
            bf16x8 kf = *(const bf16x8*)(Kbase + (jt * 16 + l15) * 128 + cbyte);
            s[jt] = __builtin_amdgcn_mfma_f32_16x16x32_bf16(kf, qf[ks], s[jt], 0, 0, 0);
          }
        }
        __builtin_amdgcn_s_setprio(0);

        if (kt * 64 + 63 > qbase) {
          int qg = qbase + l15;
#pragma unroll
          for (int jt = 0; jt < 4; ++jt)
#pragma unroll
            for (int r = 0; r < 4; ++r) {
              int kg = kt * 64 + jt * 16 + lhi * 4 + r;
              if (kg > qg) s[jt][r] = -1e30f;
            }
        }

        float mr = fmaxf(fmaxf(s[0][0], s[0][1]), fmaxf(s[0][2], s[0][3]));
#pragma unroll
        for (int jt = 1; jt < 4; ++jt)
          mr = fmaxf(mr, fmaxf(fmaxf(s[jt][0], s[jt][1]), fmaxf(s[jt][2], s[jt][3])));
        mr = fmaxf(mr, __shfl_xor(mr, 16));
        mr = fmaxf(mr, __shfl_xor(mr, 32));
        if (__any(mr > m + 8.f)) {
          float mn = fmaxf(m, mr);
          float sc = exp2f(m - mn);
          l *= sc;
          m = mn;
#pragma unroll
          for (int r = 0; r < 4; ++r) {
            float so = __shfl(sc, lhi * 4 + r);
#pragma unroll
            for (int f = 0; f < 4; ++f) o[f][r] *= so;
          }
        }

        float rs = 0.f;
#pragma unroll
        for (int jt = 0; jt < 4; ++jt)
#pragma unroll
          for (int r = 0; r < 4; ++r) {
            float pv = exp2f(s[jt][r] - m);
            s[jt][r] = pv;
            rs += pv;
          }
        rs += __shfl_xor(rs, 16);
        rs += __shfl_xor(rs, 32);
        l += rs;

#pragma unroll
        for (int jt = 0; jt < 4; ++jt) {
          uint32_t lo, hi;
          asm("v_cvt_pk_bf16_f32 %0, %1, %2"
              : "=v"(lo) : "v"(s[jt][0]), "v"(s[jt][1]));
          asm("v_cvt_pk_bf16_f32 %0, %1, %2"
              : "=v"(hi) : "v"(s[jt][2]), "v"(s[jt][3]));
          uint2 pk; pk.x = lo; pk.y = hi;
          *(uint2*)&Ps[wv][l15 * 72 + jt * 16 + lhi * 4] = pk;
        }
        __builtin_amdgcn_s_setprio(1);
#pragma unroll
        for (int ks = 0; ks < 2; ++ks) {
          const int cbyte = ks ? cb1 : cb0;
          bf16x8 pf = *(const bf16x8*)&Ps[wv][l15 * 72 + ks * 32 + lhi * 8];
#pragma unroll
          for (int f = 0; f < 4; ++f) {
            bf16x8 vfr = *(const bf16x8*)(Vbase + (f * 16 + l15) * 128 + cbyte);
            o[f] = __builtin_amdgcn_mfma_f32_16x16x32_bf16(pf, vfr, o[f], 0, 0, 0);
          }
        }
        __builtin_amdgcn_s_setprio(0);
      }
    }

#pragma unroll
    for (int r = 0; r < 4; ++r) {
      float ld = __shfl(l, lhi * 4 + r);
      float inv = 1.f / ld;
      int t = qbase + lhi * 4 + r;
#pragma unroll
      for (int f = 0; f < 4; ++f)
        O[((size_t)(b * 2048 + t)) * 1024 + h * 64 + f * 16 + l15] = f2bf(o[f][r] * inv);
    }
  }
#undef STAGEKV
}

extern "C" void kernel_launch(void* const* d_in, const int* in_sizes, int n_in,
                              void* d_out, int out_size, void* d_ws, size_t ws_size,
                              hipStream_t stream) {
  const float* x   = (const float*)d_in[0];
  const float* Wq  = (const float*)d_in[1];
  const float* Wk  = (const float*)d_in[2];
  const float* Wv  = (const float*)d_in[3];
  const float* Wo  = (const float*)d_in[4];
  const float* bo  = (const float*)d_in[5];
  const float* W1  = (const float*)d_in[6];
  const float* b1  = (const float*)d_in[7];
  const float* W2  = (const float*)d_in[8];
  const float* b2  = (const float*)d_in[9];
  const float* g1  = (const float*)d_in[10];
  const float* be1 = (const float*)d_in[11];
  const float* g2  = (const float*)d_in[12];
  const float* be2 = (const float*)d_in[13];

  char* p = (char*)d_ws;
  auto alloc = [&](size_t bytes) {
    char* r = p;
    p += (bytes + 255) & ~(size_t)255;
    return r;
  };
  u16* WqkvT = (u16*)alloc(3072ull * 1024 * 2);
  u16* WoT   = (u16*)alloc(1024ull * 1024 * 2);
  u16* W1T   = (u16*)alloc(4096ull * 1024 * 2);
  u16* W2T   = (u16*)alloc(1024ull * 4096 * 2);
  u16* hln   = (u16*)alloc(8192ull * 1024 * 2);
  u16* Qbuf  = (u16*)alloc(8192ull * 1024 * 2);
  u16* Kbuf  = (u16*)alloc(8192ull * 1024 * 2);
  u16* VTbuf = (u16*)alloc(8192ull * 1024 * 2);
  float* x2  = (float*)alloc(8192ull * 1024 * 4);
  u16* ff1   = (u16*)alloc(8192ull * 4096 * 2);
  u16* Oattn = hln;   // hln dead after QKV GEMM
  u16* h2    = Qbuf;  // Qbuf dead after attention
  if ((size_t)(p - (char*)d_ws) > ws_size) return;

  dim3 tb(32, 8);
  transpose_w<<<dim3(32, 32), tb, 0, stream>>>(Wq, WqkvT, 1024, 1024);
  transpose_w<<<dim3(32, 32), tb, 0, stream>>>(Wk, WqkvT + 1024 * 1024, 1024, 1024);
  transpose_w<<<dim3(32, 32), tb, 0, stream>>>(Wv, WqkvT + 2048 * 1024, 1024, 1024);
  transpose_w<<<dim3(32, 32), tb, 0, stream>>>(Wo, WoT, 1024, 1024);
  transpose_w<<<dim3(128, 32), tb, 0, stream>>>(W1, W1T, 1024, 4096);
  transpose_w<<<dim3(32, 128), tb, 0, stream>>>(W2, W2T, 4096, 1024);

  ln_kernel<<<8192, 256, 0, stream>>>(x, g1, be1, hln);

  gemm8p<0><<<dim3(24, 32), 512, 0, stream>>>(hln, WqkvT, 8192, 3072, 1024,
                                              nullptr, nullptr, nullptr,
                                              Qbuf, Kbuf, VTbuf);

  attn_kernel<<<dim3(8, 64), 512, 0, stream>>>(Qbuf, Kbuf, VTbuf, Oattn);

  gemm8p<1><<<dim3(8, 32), 512, 0, stream>>>(Oattn, WoT, 8192, 1024, 1024,
                                             bo, x, x2, nullptr, nullptr, nullptr);

  ln_kernel<<<8192, 256, 0, stream>>>(x2, g2, be2, h2);

  gemm8p<2><<<dim3(32, 32), 512, 0, stream>>>(h2, W1T, 8192, 4096, 1024,
                                              b1, nullptr, nullptr, ff1, nullptr, nullptr);

  gemm8p<3><<<dim3(8, 32), 512, 0, stream>>>(ff1, W2T, 8192, 1024, 4096,
                                             b2, x2, (float*)d_out, nullptr, nullptr, nullptr);
}

// Round 9
// 393.036 us; speedup vs baseline: 1.1370x; 1.0276x over previous
//
#include <hip/hip_runtime.h>
#include <cstdint>
#include <cstddef>

typedef unsigned short u16;
typedef __attribute__((ext_vector_type(8))) short bf16x8;
typedef __attribute__((ext_vector_type(4))) float f32x4;
typedef __attribute__((address_space(1))) const unsigned int gu32;
typedef __attribute__((address_space(3))) unsigned int lu32;

#define QSCALE 0.1803368801111204f  // 0.125 * log2(e): softmax done in exp2 domain

__device__ __forceinline__ u16 f2bf(float f) {
  uint32_t u = __float_as_uint(f);
  u += 0x7fffu + ((u >> 16) & 1u);
  return (u16)(u >> 16);
}

// ---------------- transpose fp32 (K,N) -> bf16 (N,K) ----------------
__global__ __launch_bounds__(256) void transpose_w(const float* __restrict__ W,
                                                   u16* __restrict__ WT,
                                                   int K, int N) {
  __shared__ float t[32][33];
  int n0 = blockIdx.x * 32, k0 = blockIdx.y * 32;
  for (int i = threadIdx.y; i < 32; i += 8)
    t[i][threadIdx.x] = W[(size_t)(k0 + i) * N + n0 + threadIdx.x];
  __syncthreads();
  for (int i = threadIdx.y; i < 32; i += 8)
    WT[(size_t)(n0 + i) * K + k0 + threadIdx.x] = f2bf(t[threadIdx.x][i]);
}

// ---------------- layernorm fp32 row(1024) -> bf16 ----------------
__global__ __launch_bounds__(256) void ln_kernel(const float* __restrict__ x,
                                                 const float* __restrict__ g,
                                                 const float* __restrict__ b,
                                                 u16* __restrict__ out) {
  int row = blockIdx.x;
  const float4 v = *(const float4*)(x + (size_t)row * 1024 + threadIdx.x * 4);
  float s = v.x + v.y + v.z + v.w;
  float ss = v.x * v.x + v.y * v.y + v.z * v.z + v.w * v.w;
#pragma unroll
  for (int d = 1; d < 64; d <<= 1) { s += __shfl_xor(s, d); ss += __shfl_xor(ss, d); }
  __shared__ float rs_[4], rss_[4];
  int wv = threadIdx.x >> 6;
  if ((threadIdx.x & 63) == 0) { rs_[wv] = s; rss_[wv] = ss; }
  __syncthreads();
  s = rs_[0] + rs_[1] + rs_[2] + rs_[3];
  ss = rss_[0] + rss_[1] + rss_[2] + rss_[3];
  float mu = s * (1.f / 1024.f);
  float var = ss * (1.f / 1024.f) - mu * mu;
  float rstd = rsqrtf(var + 1e-5f);
  float4 gv = *(const float4*)(g + threadIdx.x * 4);
  float4 bv = *(const float4*)(b + threadIdx.x * 4);
  uint32_t lo = (uint32_t)f2bf((v.x - mu) * rstd * gv.x + bv.x) |
                ((uint32_t)f2bf((v.y - mu) * rstd * gv.y + bv.y) << 16);
  uint32_t hi = (uint32_t)f2bf((v.z - mu) * rstd * gv.z + bv.z) |
                ((uint32_t)f2bf((v.w - mu) * rstd * gv.w + bv.w) << 16);
  uint2 o; o.x = lo; o.y = hi;
  *(uint2*)(out + (size_t)row * 1024 + threadIdx.x * 4) = o;
}

// ---------------- deep-pipelined GEMM: C = A(bf16 MxK) * BT(bf16 NxK) ----------------
// BM=256 BN=128 BK=64, 8 waves (4Mx2N), ring-3 LDS (144KB), prefetch 2 K-tiles ahead,
// counted vmcnt (6 steady), ks-OUTER MFMA order, T2 row-XOR swizzle, T5 setprio.
// LDS-staged coalesced epilogue for bf16 outputs (MODE 0).
// MODE 0: QKV (N=3072) -> Q2[B,T,1024]*QSCALE / K2[B,T,1024] / VT[B,H,HD,T]
// MODE 1: PROJ -> outf = acc + bias + resid      (fp32)
// MODE 3: FF2  -> outf = relu(acc + bias) + resid (fp32)
#define STAGEA(slot, tnext, is)                                               \
  __builtin_amdgcn_global_load_lds(                                           \
      (gu32*)((const char*)(A + (size_t)(bm * 256 + (is) * 64 + srow) * K +   \
                            (size_t)(tnext) * 64) + ssw),                     \
      (lu32*)&lds[(slot) * 24576 + (is) * 4096 + wid * 512], 16, 0, 0)
#define STAGEB(slot, tnext, is)                                               \
  __builtin_amdgcn_global_load_lds(                                           \
      (gu32*)((const char*)(BT + (size_t)(bn * 128 + (is) * 64 + srow) * K +  \
                            (size_t)(tnext) * 64) + ssw),                     \
      (lu32*)&lds[(slot) * 24576 + 16384 + (is) * 4096 + wid * 512], 16, 0, 0)

template <int MODE>
__global__ __launch_bounds__(512, 2) void gemm8p(
    const u16* __restrict__ A, const u16* __restrict__ BT,
    int M, int N, int K,
    const float* __restrict__ bias, const float* __restrict__ resid,
    float* __restrict__ outf,
    u16* __restrict__ ob0, u16* __restrict__ ob1, u16* __restrict__ ob2) {
  __shared__ __align__(16) u16 lds[73728];  // 3 x (A 256x64 + B 128x64) = 144 KB
  const int tid = threadIdx.x, lane = tid & 63, wid = tid >> 6;
  const int wr = wid >> 1, wc = wid & 1;
  const int bm = blockIdx.y, bn = blockIdx.x;
  const int l15 = lane & 15, lhi = lane >> 4;
  const int srow = tid >> 3;
  const int ssw = ((tid & 7) * 16) ^ ((srow & 7) << 4);
  const int cs0 = (lhi * 8) ^ ((l15 & 7) << 3);
  const int cs1 = (32 + lhi * 8) ^ ((l15 & 7) << 3);
  const int arow = (wr * 64 + l15) * 64;
  const int brow = (wc * 64 + l15) * 64;

  f32x4 acc[4][4];
#pragma unroll
  for (int i = 0; i < 4; ++i)
#pragma unroll
    for (int j = 0; j < 4; ++j) acc[i][j] = (f32x4){0.f, 0.f, 0.f, 0.f};

  const int NT = K >> 6;

  // prologue: stage tiles 0,1 into slots 0,1 (loop stages tile 2 at t=0)
#pragma unroll
  for (int t0 = 0; t0 < 2; ++t0) {
    STAGEA(t0, t0, 0); STAGEA(t0, t0, 1); STAGEA(t0, t0, 2); STAGEA(t0, t0, 3);
    STAGEB(t0, t0, 0); STAGEB(t0, t0, 1);
  }
  asm volatile("s_waitcnt vmcnt(6)" ::: "memory");  // tile 0 landed
  __builtin_amdgcn_s_barrier();

  int s = 0, sn = 2;
  for (int t = 0; t < NT; ++t) {
    const bool hasPre = (t + 2) < NT;
    const int aoff = s * 24576, boff = s * 24576 + 16384;

    bf16x8 bfr[4][2], afr[2][2];
#pragma unroll
    for (int ni = 0; ni < 4; ++ni) {
      bfr[ni][0] = *(const bf16x8*)&lds[boff + brow + ni * 1024 + cs0];
      bfr[ni][1] = *(const bf16x8*)&lds[boff + brow + ni * 1024 + cs1];
    }
    afr[0][0] = *(const bf16x8*)&lds[aoff + arow + cs0];
    afr[0][1] = *(const bf16x8*)&lds[aoff + arow + cs1];
    afr[1][0] = *(const bf16x8*)&lds[aoff + arow + 1024 + cs0];
    afr[1][1] = *(const bf16x8*)&lds[aoff + arow + 1024 + cs1];
    if (hasPre) { STAGEA(sn, t + 2, 0); STAGEA(sn, t + 2, 1); STAGEB(sn, t + 2, 0); }
    __builtin_amdgcn_s_barrier();
    __builtin_amdgcn_s_setprio(1);
#pragma unroll
    for (int ks = 0; ks < 2; ++ks)
#pragma unroll
      for (int ml = 0; ml < 2; ++ml)
#pragma unroll
        for (int ni = 0; ni < 4; ++ni)
          acc[ml][ni] = __builtin_amdgcn_mfma_f32_16x16x32_bf16(afr[ml][ks], bfr[ni][ks], acc[ml][ni], 0, 0, 0);
    __builtin_amdgcn_s_setprio(0);
    __builtin_amdgcn_s_barrier();

    afr[0][0] = *(const bf16x8*)&lds[aoff + arow + 2048 + cs0];
    afr[0][1] = *(const bf16x8*)&lds[aoff + arow + 2048 + cs1];
    afr[1][0] = *(const bf16x8*)&lds[aoff + arow + 3072 + cs0];
    afr[1][1] = *(const bf16x8*)&lds[aoff + arow + 3072 + cs1];
    if (hasPre) { STAGEA(sn, t + 2, 2); STAGEA(sn, t + 2, 3); STAGEB(sn, t + 2, 1); }
    __builtin_amdgcn_s_barrier();
    __builtin_amdgcn_s_setprio(1);
#pragma unroll
    for (int ks = 0; ks < 2; ++ks)
#pragma unroll
      for (int ml = 0; ml < 2; ++ml)
#pragma unroll
        for (int ni = 0; ni < 4; ++ni)
          acc[2 + ml][ni] = __builtin_amdgcn_mfma_f32_16x16x32_bf16(afr[ml][ks], bfr[ni][ks], acc[2 + ml][ni], 0, 0, 0);
    __builtin_amdgcn_s_setprio(0);
    if (hasPre) {
      asm volatile("s_waitcnt vmcnt(6)" ::: "memory");
    } else if (t + 1 < NT) {
      asm volatile("s_waitcnt vmcnt(0)" ::: "memory");
    }
    __builtin_amdgcn_s_barrier();

    s = (s == 2) ? 0 : s + 1;
    sn = (sn == 2) ? 0 : sn + 1;
  }

  // ---------------- epilogue ----------------
  if (MODE == 0) {
    // LDS-staged coalesced epilogue (all waves past final barrier; LDS free)
    char* ep = (char*)lds;
    const bool vmode = (bn >= 16);
    if (vmode) {
      // V part: LDS [128 col][264 u16 pitch], b64-packed r-quads -> VT rows
#pragma unroll
      for (int mi = 0; mi < 4; ++mi)
#pragma unroll
        for (int ni = 0; ni < 4; ++ni) {
          uint32_t lo, hi;
          asm("v_cvt_pk_bf16_f32 %0, %1, %2"
              : "=v"(lo) : "v"(acc[mi][ni][0]), "v"(acc[mi][ni][1]));
          asm("v_cvt_pk_bf16_f32 %0, %1, %2"
              : "=v"(hi) : "v"(acc[mi][ni][2]), "v"(acc[mi][ni][3]));
          uint2 pk; pk.x = lo; pk.y = hi;
          int c_local = wc * 64 + ni * 16 + l15;
          int rb = wr * 64 + mi * 16 + lhi * 4;
          *(uint2*)(ep + c_local * 528 + rb * 2) = pk;
        }
    } else {
      // Q/K: LDS [256 row][136 u16 pitch], scalar b16 writes
      const float sc = (bn < 8) ? QSCALE : 1.f;
#pragma unroll
      for (int mi = 0; mi < 4; ++mi)
#pragma unroll
        for (int ni = 0; ni < 4; ++ni) {
          int c_local = wc * 64 + ni * 16 + l15;
          int rb = wr * 64 + mi * 16 + lhi * 4;
#pragma unroll
          for (int r = 0; r < 4; ++r) {
            *(u16*)(ep + (rb + r) * 272 + c_local * 2) = f2bf(acc[mi][ni][r] * sc);
          }
        }
    }
    __syncthreads();
    if (vmode) {
#pragma unroll
      for (int i = 0; i < 8; ++i) {
        int idx = i * 512 + tid;
        int c = idx >> 5, tc = idx & 31;
        uint4 d4 = *(const uint4*)(ep + c * 528 + tc * 16);
        int cm = bn * 128 + c - 2048, hh = cm >> 6, dd = cm & 63;
        size_t bh = (size_t)((bm >> 3) * 16 + hh);
        int t0 = (bm & 7) * 256;
        *(uint4*)&ob2[(bh * 64 + dd) * 2048 + t0 + tc * 8] = d4;
      }
    } else {
#pragma unroll
      for (int i = 0; i < 8; ++i) {
        int idx = i * 512 + tid;
        int row = idx >> 4, cc = idx & 15;
        uint4 d4 = *(const uint4*)(ep + row * 272 + cc * 16);
        size_t rg = (size_t)(bm * 256 + row);
        int colg = bn * 128 + cc * 8;
        if (colg < 1024)
          *(uint4*)&ob0[rg * 1024 + colg] = d4;        // Q2 (pre-scaled)
        else
          *(uint4*)&ob1[rg * 1024 + colg - 1024] = d4; // K2
      }
    }
  } else {
#pragma unroll
    for (int mi = 0; mi < 4; ++mi) {
#pragma unroll
      for (int ni = 0; ni < 4; ++ni) {
        int col = bn * 128 + wc * 64 + ni * 16 + l15;
        int rbase = bm * 256 + wr * 64 + mi * 16 + lhi * 4;
#pragma unroll
        for (int r = 0; r < 4; ++r) {
          float v = acc[mi][ni][r];
          int rg = rbase + r;
          if (MODE == 1) {
            outf[(size_t)rg * N + col] = v + bias[col] + resid[(size_t)rg * N + col];
          } else {
            outf[(size_t)rg * N + col] = fmaxf(v + bias[col], 0.f) + resid[(size_t)rg * N + col];
          }
        }
      }
    }
  }
}

// ---------------- 256x256 deep GEMM for FF1: out = bf16(relu(A*W1T + b1)) ----------
// BM=BN=256 BK=64, 8 waves (2M x 4N), wave tile 128x64, dbuf-2 LDS (128 KB),
// 4 phases/K-tile of 16 MFMA (barrier/setprio bracket), stage t+1 in phase 0,
// T2 XOR swizzle, LDS-staged coalesced epilogue in 2 half-passes.
#define SA256(buf, t, is)                                                     \
  __builtin_amdgcn_global_load_lds(                                           \
      (gu32*)((const char*)(A + (size_t)(bm * 256 + (is) * 64 + srow) * K +   \
                            (size_t)(t) * 64) + ssw),                         \
      (lu32*)&lds[(buf) * 32768 + (is) * 4096 + wid * 512], 16, 0, 0)
#define SB256(buf, t, is)                                                     \
  __builtin_amdgcn_global_load_lds(                                           \
      (gu32*)((const char*)(BT + (size_t)(bn * 256 + (is) * 64 + srow) * K +  \
                            (size_t)(t) * 64) + ssw),                         \
      (lu32*)&lds[(buf) * 32768 + 16384 + (is) * 4096 + wid * 512], 16, 0, 0)

__global__ __launch_bounds__(512, 2) void gemm256(
    const u16* __restrict__ A, const u16* __restrict__ BT,
    int M, int N, int K,
    const float* __restrict__ bias, u16* __restrict__ out) {
  __shared__ __align__(16) u16 lds[65536];  // 2 x (A 256x64 + B 256x64) = 128 KB
  const int tid = threadIdx.x, lane = tid & 63, wid = tid >> 6;
  const int wr = wid >> 2, wc = wid & 3;  // 2M x 4N; wave tile 128x64
  const int bm = blockIdx.y, bn = blockIdx.x;
  const int l15 = lane & 15, lhi = lane >> 4;
  const int srow = tid >> 3;
  const int ssw = ((tid & 7) * 16) ^ ((srow & 7) << 4);
  const int rsw = (l15 & 7) << 4;
  const int cbyte0 = (lhi * 16) ^ rsw;
  const int cbyte1 = (64 + lhi * 16) ^ rsw;

  f32x4 acc[8][4];
#pragma unroll
  for (int i = 0; i < 8; ++i)
#pragma unroll
    for (int j = 0; j < 4; ++j) acc[i][j] = (f32x4){0.f, 0.f, 0.f, 0.f};

  const int NT = K >> 6;

  // prologue: stage tile 0 into buf 0
#pragma unroll
  for (int is = 0; is < 4; ++is) SA256(0, 0, is);
#pragma unroll
  for (int is = 0; is < 4; ++is) SB256(0, 0, is);
  asm volatile("s_waitcnt vmcnt(0)" ::: "memory");
  __builtin_amdgcn_s_barrier();

  for (int t = 0; t < NT; ++t) {
    const int buf = t & 1;
    const char* Ap = (const char*)lds + buf * 65536;
    const char* Bp = Ap + 32768;
    const bool hasNext = (t + 1) < NT;

    bf16x8 bfr[4], afr[4];
#pragma unroll
    for (int ph = 0; ph < 4; ++ph) {
      const int ks = ph >> 1, mg = ph & 1;
      const int cb = ks ? cbyte1 : cbyte0;
      if (mg == 0) {
#pragma unroll
        for (int ni = 0; ni < 4; ++ni)
          bfr[ni] = *(const bf16x8*)(Bp + (wc * 64 + ni * 16 + l15) * 128 + cb);
      }
#pragma unroll
      for (int i = 0; i < 4; ++i)
        afr[i] = *(const bf16x8*)(Ap + (wr * 128 + (mg * 4 + i) * 16 + l15) * 128 + cb);
      if (ph == 0 && hasNext) {
        SA256(buf ^ 1, t + 1, 0); SA256(buf ^ 1, t + 1, 1);
        SA256(buf ^ 1, t + 1, 2); SA256(buf ^ 1, t + 1, 3);
        SB256(buf ^ 1, t + 1, 0); SB256(buf ^ 1, t + 1, 1);
        SB256(buf ^ 1, t + 1, 2); SB256(buf ^ 1, t + 1, 3);
      }
      __builtin_amdgcn_s_barrier();
      __builtin_amdgcn_s_setprio(1);
#pragma unroll
      for (int i = 0; i < 4; ++i)
#pragma unroll
        for (int ni = 0; ni < 4; ++ni)
          acc[mg * 4 + i][ni] = __builtin_amdgcn_mfma_f32_16x16x32_bf16(afr[i], bfr[ni], acc[mg * 4 + i][ni], 0, 0, 0);
      __builtin_amdgcn_s_setprio(0);
      if (ph == 3 && hasNext) asm volatile("s_waitcnt vmcnt(0)" ::: "memory");
      __builtin_amdgcn_s_barrier();
    }
  }

  // ---- epilogue: 2 half-passes, LDS [128 row][264 u16 pitch], coalesced stores ----
  char* ep = (char*)lds;
#pragma unroll
  for (int h = 0; h < 2; ++h) {
    __syncthreads();
    if (wr == h) {
#pragma unroll
      for (int ni = 0; ni < 4; ++ni) {
        int c_local = wc * 64 + ni * 16 + l15;
        float bv = bias[bn * 256 + c_local];
#pragma unroll
        for (int mi = 0; mi < 8; ++mi) {
          int rb = mi * 16 + lhi * 4;
#pragma unroll
          for (int r = 0; r < 4; ++r) {
            float v = fmaxf(acc[mi][ni][r] + bv, 0.f);
            *(u16*)(ep + (rb + r) * 528 + c_local * 2) = f2bf(v);
          }
        }
      }
    }
    __syncthreads();
#pragma unroll
    for (int i = 0; i < 8; ++i) {
      int idx = i * 512 + tid;
      int row = idx >> 5, cc = idx & 31;
      uint4 d4 = *(const uint4*)(ep + row * 528 + cc * 16);
      size_t rg = (size_t)(bm * 256 + h * 128 + row);
      *(uint4*)&out[rg * (size_t)N + bn * 256 + cc * 8] = d4;
    }
  }
}

// ---------------- causal flash attention ----------------
// 8 waves x 16 q-rows; chunk pairing (15-p, p); Q2/K2 in natural [B,T,1024] layout,
// VT [B,H,HD,T]. Swapped QK^T in exp2 domain, global_load_lds K/V staging
// (XOR swizzle, dbuf), defer-max, cvt_pk P-pack, setprio on MFMA clusters.
__global__ __launch_bounds__(512) void attn_kernel(
    const u16* __restrict__ Qb, const u16* __restrict__ Kb,
    const u16* __restrict__ VTb, u16* __restrict__ O) {
  const int p = blockIdx.x;  // 0..7
  const int bh = blockIdx.y;
  const int b = bh >> 4, h = bh & 15;
  const u16* Q = Qb + (size_t)b * 2048 * 1024 + h * 64;   // natural layout
  const u16* Kn = Kb + (size_t)b * 2048 * 1024 + h * 64;
  const u16* VT = VTb + (size_t)bh * 64 * 2048;
  const int tid = threadIdx.x, lane = tid & 63, wv = tid >> 6;
  const int l15 = lane & 15, lhi = lane >> 4;
  const int srow = tid >> 3;             // 0..63
  const int scol16 = (tid & 7) * 16;     // byte within 128B row
  const int sw = scol16 ^ ((srow & 7) << 4);  // inverse-swizzled src byte
  const int rswz = (l15 & 7) << 4;
  const int cb0 = (lhi * 16) ^ rswz;     // swizzled byte col, ks=0
  const int cb1 = (64 + lhi * 16) ^ rswz;

  __shared__ __align__(16) u16 KV[2][2][4096];  // [slot][K,V][64x64] = 32 KB
  __shared__ u16 Ps[8][16 * 72];                // 18 KB

#define STAGEKV(slot, kt)                                                     \
  do {                                                                        \
    __builtin_amdgcn_global_load_lds(                                         \
        (gu32*)((const char*)(Kn + (size_t)((kt)*64 + srow) * 1024) + sw),    \
        (lu32*)&KV[slot][0][wv * 512], 16, 0, 0);                             \
    __builtin_amdgcn_global_load_lds(                                         \
        (gu32*)((const char*)(VT + (size_t)srow * 2048 + (kt)*64) + sw),      \
        (lu32*)&KV[slot][1][wv * 512], 16, 0, 0);                             \
  } while (0)

#pragma unroll
  for (int pass = 0; pass < 2; ++pass) {
    const int chunk = pass ? p : (15 - p);
    const int qbase = chunk * 128 + wv * 16;
    const int nkt = 2 * chunk + 2;

    bf16x8 qf[2];
#pragma unroll
    for (int ks = 0; ks < 2; ++ks)
      qf[ks] = *(const bf16x8*)&Q[(size_t)(qbase + l15) * 1024 + ks * 32 + lhi * 8];

    f32x4 o[4];
#pragma unroll
    for (int f = 0; f < 4; ++f) o[f] = (f32x4){0.f, 0.f, 0.f, 0.f};
    float m = -1e30f;
    float l = 0.f;

    __syncthreads();  // prior pass's LDS reads complete across all waves
    STAGEKV(0, 0);

    for (int kt = 0; kt < nkt; ++kt) {
      const int cs = kt & 1;
      asm volatile("s_waitcnt vmcnt(0)" ::: "memory");
      __syncthreads();
      if (kt + 1 < nkt) STAGEKV(cs ^ 1, kt + 1);

      if (kt * 64 <= qbase + 15) {
        const char* Kbase = (const char*)&KV[cs][0][0];
        const char* Vbase = (const char*)&KV[cs][1][0];

        f32x4 s[4];
#pragma unroll
        for (int jt = 0; jt < 4; ++jt) s[jt] = (f32x4){0.f, 0.f, 0.f, 0.f};
        __builtin_amdgcn_s_setprio(1);
#pragma unroll
        for (int ks = 0; ks < 2; ++ks) {
          const int cbyte = ks ? cb1 : cb0;
#pragma unroll
          for (int jt = 0; jt < 4; ++jt) {
            bf16x8 kf = *(const bf16x8*)(Kbase + (jt * 16 + l15) * 128 + cbyte);
            s[jt] = __builtin_amdgcn_mfma_f32_16x16x32_bf16(kf, qf[ks], s[jt], 0, 0, 0);
          }
        }
        __builtin_amdgcn_s_setprio(0);

        if (kt * 64 + 63 > qbase) {
          int qg = qbase + l15;
#pragma unroll
          for (int jt = 0; jt < 4; ++jt)
#pragma unroll
            for (int r = 0; r < 4; ++r) {
              int kg = kt * 64 + jt * 16 + lhi * 4 + r;
              if (kg > qg) s[jt][r] = -1e30f;
            }
        }

        float mr = fmaxf(fmaxf(s[0][0], s[0][1]), fmaxf(s[0][2], s[0][3]));
#pragma unroll
        for (int jt = 1; jt < 4; ++jt)
          mr = fmaxf(mr, fmaxf(fmaxf(s[jt][0], s[jt][1]), fmaxf(s[jt][2], s[jt][3])));
        mr = fmaxf(mr, __shfl_xor(mr, 16));
        mr = fmaxf(mr, __shfl_xor(mr, 32));
        if (__any(mr > m + 8.f)) {
          float mn = fmaxf(m, mr);
          float sc = exp2f(m - mn);
          l *= sc;
          m = mn;
#pragma unroll
          for (int r = 0; r < 4; ++r) {
            float so = __shfl(sc, lhi * 4 + r);
#pragma unroll
            for (int f = 0; f < 4; ++f) o[f][r] *= so;
          }
        }

        float rs = 0.f;
#pragma unroll
        for (int jt = 0; jt < 4; ++jt)
#pragma unroll
          for (int r = 0; r < 4; ++r) {
            float pv = exp2f(s[jt][r] - m);
            s[jt][r] = pv;
            rs += pv;
          }
        rs += __shfl_xor(rs, 16);
        rs += __shfl_xor(rs, 32);
        l += rs;

#pragma unroll
        for (int jt = 0; jt < 4; ++jt) {
          uint32_t lo, hi;
          asm("v_cvt_pk_bf16_f32 %0, %1, %2"
              : "=v"(lo) : "v"(s[jt][0]), "v"(s[jt][1]));
          asm("v_cvt_pk_bf16_f32 %0, %1, %2"
              : "=v"(hi) : "v"(s[jt][2]), "v"(s[jt][3]));
          uint2 pk; pk.x = lo; pk.y = hi;
          *(uint2*)&Ps[wv][l15 * 72 + jt * 16 + lhi * 4] = pk;
        }
        __builtin_amdgcn_s_setprio(1);
#pragma unroll
        for (int ks = 0; ks < 2; ++ks) {
          const int cbyte = ks ? cb1 : cb0;
          bf16x8 pf = *(const bf16x8*)&Ps[wv][l15 * 72 + ks * 32 + lhi * 8];
#pragma unroll
          for (int f = 0; f < 4; ++f) {
            bf16x8 vfr = *(const bf16x8*)(Vbase + (f * 16 + l15) * 128 + cbyte);
            o[f] = __builtin_amdgcn_mfma_f32_16x16x32_bf16(pf, vfr, o[f], 0, 0, 0);
          }
        }
        __builtin_amdgcn_s_setprio(0);
      }
    }

#pragma unroll
    for (int r = 0; r < 4; ++r) {
      float ld = __shfl(l, lhi * 4 + r);
      float inv = 1.f / ld;
      int t = qbase + lhi * 4 + r;
#pragma unroll
      for (int f = 0; f < 4; ++f)
        O[((size_t)(b * 2048 + t)) * 1024 + h * 64 + f * 16 + l15] = f2bf(o[f][r] * inv);
    }
  }
#undef STAGEKV
}

extern "C" void kernel_launch(void* const* d_in, const int* in_sizes, int n_in,
                              void* d_out, int out_size, void* d_ws, size_t ws_size,
                              hipStream_t stream) {
  const float* x   = (const float*)d_in[0];
  const float* Wq  = (const float*)d_in[1];
  const float* Wk  = (const float*)d_in[2];
  const float* Wv  = (const float*)d_in[3];
  const float* Wo  = (const float*)d_in[4];
  const float* bo  = (const float*)d_in[5];
  const float* W1  = (const float*)d_in[6];
  const float* b1  = (const float*)d_in[7];
  const float* W2  = (const float*)d_in[8];
  const float* b2  = (const float*)d_in[9];
  const float* g1  = (const float*)d_in[10];
  const float* be1 = (const float*)d_in[11];
  const float* g2  = (const float*)d_in[12];
  const float* be2 = (const float*)d_in[13];

  char* p = (char*)d_ws;
  auto alloc = [&](size_t bytes) {
    char* r = p;
    p += (bytes + 255) & ~(size_t)255;
    return r;
  };
  u16* WqkvT = (u16*)alloc(3072ull * 1024 * 2);
  u16* WoT   = (u16*)alloc(1024ull * 1024 * 2);
  u16* W1T   = (u16*)alloc(4096ull * 1024 * 2);
  u16* W2T   = (u16*)alloc(1024ull * 4096 * 2);
  u16* hln   = (u16*)alloc(8192ull * 1024 * 2);
  u16* Qbuf  = (u16*)alloc(8192ull * 1024 * 2);
  u16* Kbuf  = (u16*)alloc(8192ull * 1024 * 2);
  u16* VTbuf = (u16*)alloc(8192ull * 1024 * 2);
  float* x2  = (float*)alloc(8192ull * 1024 * 4);
  u16* ff1   = (u16*)alloc(8192ull * 4096 * 2);
  u16* Oattn = hln;   // hln dead after QKV GEMM
  u16* h2    = Qbuf;  // Qbuf dead after attention
  if ((size_t)(p - (char*)d_ws) > ws_size) return;

  dim3 tb(32, 8);
  transpose_w<<<dim3(32, 32), tb, 0, stream>>>(Wq, WqkvT, 1024, 1024);
  transpose_w<<<dim3(32, 32), tb, 0, stream>>>(Wk, WqkvT + 1024 * 1024, 1024, 1024);
  transpose_w<<<dim3(32, 32), tb, 0, stream>>>(Wv, WqkvT + 2048 * 1024, 1024, 1024);
  transpose_w<<<dim3(32, 32), tb, 0, stream>>>(Wo, WoT, 1024, 1024);
  transpose_w<<<dim3(128, 32), tb, 0, stream>>>(W1, W1T, 1024, 4096);
  transpose_w<<<dim3(32, 128), tb, 0, stream>>>(W2, W2T, 4096, 1024);

  ln_kernel<<<8192, 256, 0, stream>>>(x, g1, be1, hln);

  gemm8p<0><<<dim3(24, 32), 512, 0, stream>>>(hln, WqkvT, 8192, 3072, 1024,
                                              nullptr, nullptr, nullptr,
                                              Qbuf, Kbuf, VTbuf);

  attn_kernel<<<dim3(8, 64), 512, 0, stream>>>(Qbuf, Kbuf, VTbuf, Oattn);

  gemm8p<1><<<dim3(8, 32), 512, 0, stream>>>(Oattn, WoT, 8192, 1024, 1024,
                                             bo, x, x2, nullptr, nullptr, nullptr);

  ln_kernel<<<8192, 256, 0, stream>>>(x2, g2, be2, h2);

  gemm256<<<dim3(16, 32), 512, 0, stream>>>(h2, W1T, 8192, 4096, 1024, b1, ff1);

  gemm8p<3><<<dim3(8, 32), 512, 0, stream>>>(ff1, W2T, 8192, 1024, 4096,
                                             b2, x2, (float*)d_out, nullptr, nullptr, nullptr);
}